// Round 3
// baseline (271.743 us; speedup 1.0000x reference)
//
#include <hip/hip_runtime.h>
#include <hip/hip_fp16.h>

#define CH 16
#define NPIX (4 * 512 * 512)
#define NBINS 4096   // 64x64 bins of 16x16 layer1 texels

// ---------------------------------------------------------------------------
// Repack one pyramid layer from [C, H, W] f32 to [H, W, C] fp16 (interleaved).
// ---------------------------------------------------------------------------
__global__ __launch_bounds__(256) void interleave_fp16_kernel(
    const float* __restrict__ src, __half* __restrict__ dst, int HW) {
  int p = blockIdx.x * blockDim.x + threadIdx.x;
  if (p >= HW) return;
  union { __half h[CH]; uint4 u[2]; } pk;
#pragma unroll
  for (int c = 0; c < CH; ++c) pk.h[c] = __float2half(src[(size_t)c * HW + p]);
  uint4* d = (uint4*)(dst + (size_t)p * CH);
  d[0] = pk.u[0];
  d[1] = pk.u[1];
}

// ---------------------------------------------------------------------------
// One bilinear corner: load 16 fp16 channels (2x uint4), FMA into f32 acc.
// ---------------------------------------------------------------------------
__device__ __forceinline__ void corner_fma(const __half* __restrict__ t,
                                           size_t texel, float w, float acc[CH]) {
  const uint4* q = (const uint4*)(t + texel * CH);
  union { uint4 u; __half2 h[4]; } a, b;
  a.u = q[0];
  b.u = q[1];
#pragma unroll
  for (int i = 0; i < 4; ++i) {
    float2 f = __half22float2(a.h[i]);
    acc[2 * i + 0] = fmaf(f.x, w, acc[2 * i + 0]);
    acc[2 * i + 1] = fmaf(f.y, w, acc[2 * i + 1]);
  }
#pragma unroll
  for (int i = 0; i < 4; ++i) {
    float2 f = __half22float2(b.h[i]);
    acc[8 + 2 * i + 0] = fmaf(f.x, w, acc[8 + 2 * i + 0]);
    acc[8 + 2 * i + 1] = fmaf(f.y, w, acc[8 + 2 * i + 1]);
  }
}

// Bilinear sample of one interleaved fp16 [H, W, C] layer into f32 acc[CH].
__device__ __forceinline__ void sample_hwc16(const __half* __restrict__ t, int W,
                                             float gx, float gy, float acc[CH]) {
  const float W1 = (float)(W - 1);
  float ix = (gx + 1.0f) * 0.5f * W1;
  float iy = (gy + 1.0f) * 0.5f * W1;
  float ix0f = floorf(ix), iy0f = floorf(iy);
  float wx1 = ix - ix0f, wy1 = iy - iy0f;
  float wx0 = 1.0f - wx1, wy0 = 1.0f - wy1;
  float ix1f = ix0f + 1.0f, iy1f = iy0f + 1.0f;
  float vx0 = (ix0f >= 0.0f && ix0f <= W1) ? 1.0f : 0.0f;
  float vx1 = (ix1f >= 0.0f && ix1f <= W1) ? 1.0f : 0.0f;
  float vy0 = (iy0f >= 0.0f && iy0f <= W1) ? 1.0f : 0.0f;
  float vy1 = (iy1f >= 0.0f && iy1f <= W1) ? 1.0f : 0.0f;
  int x0 = min(max((int)ix0f, 0), W - 1);
  int x1 = min(max((int)ix1f, 0), W - 1);
  int y0 = min(max((int)iy0f, 0), W - 1);
  int y1 = min(max((int)iy1f, 0), W - 1);
  float w00 = wy0 * wx0 * vy0 * vx0;
  float w01 = wy0 * wx1 * vy0 * vx1;
  float w10 = wy1 * wx0 * vy1 * vx0;
  float w11 = wy1 * wx1 * vy1 * vx1;
  corner_fma(t, (size_t)y0 * W + x0, w00, acc);
  corner_fma(t, (size_t)y0 * W + x1, w01, acc);
  corner_fma(t, (size_t)y1 * W + x0, w10, acc);
  corner_fma(t, (size_t)y1 * W + x1, w11, acc);
}

// ---------------------------------------------------------------------------
// Binning: bin = 16x16-texel tile at layer1 (1024^2) resolution.
// ---------------------------------------------------------------------------
__device__ __forceinline__ int bin_of(float xv, float yv) {
  int bx = min(max((int)(xv * 1023.0f), 0), 1023) >> 4;
  int by = min(max((int)(yv * 1023.0f), 0), 1023) >> 4;
  return (by << 6) + bx;
}

__global__ __launch_bounds__(256) void count_kernel(
    const float2* __restrict__ x, unsigned* __restrict__ counts) {
  int p = blockIdx.x * blockDim.x + threadIdx.x;
  float2 g = x[p];
  atomicAdd(&counts[bin_of(g.x, g.y)], 1u);
}

// Exclusive scan of 4096 counts -> cursor (one block, 1024 threads).
__global__ __launch_bounds__(1024) void scan_kernel(
    const unsigned* __restrict__ counts, unsigned* __restrict__ cursor) {
  __shared__ unsigned part[1024];
  int t = threadIdx.x;
  unsigned c0 = counts[4 * t + 0], c1 = counts[4 * t + 1];
  unsigned c2 = counts[4 * t + 2], c3 = counts[4 * t + 3];
  part[t] = c0 + c1 + c2 + c3;
  __syncthreads();
  for (int off = 1; off < 1024; off <<= 1) {
    unsigned v = (t >= off) ? part[t - off] : 0u;
    __syncthreads();
    part[t] += v;
    __syncthreads();
  }
  unsigned base = (t > 0) ? part[t - 1] : 0u;  // exclusive
  cursor[4 * t + 0] = base;
  cursor[4 * t + 1] = base + c0;
  cursor[4 * t + 2] = base + c0 + c1;
  cursor[4 * t + 3] = base + c0 + c1 + c2;
}

// Scatter pixel records into bin order: {x, y, bits(p), mask}.
__global__ __launch_bounds__(256) void scatter_kernel(
    const float2* __restrict__ x, const float* __restrict__ msk,
    unsigned* __restrict__ cursor, float4* __restrict__ pixrec) {
  int p = blockIdx.x * blockDim.x + threadIdx.x;
  float2 g = x[p];
  float m = msk[p];
  unsigned i = atomicAdd(&cursor[bin_of(g.x, g.y)], 1u);
  pixrec[i] = make_float4(g.x, g.y, __uint_as_float((unsigned)p), m);
}

// Gather in bin (texture-locality) order; write pixel-major staging ws2[p][16].
__global__ __launch_bounds__(256) void gather_binned_kernel(
    const float4* __restrict__ pixrec,
    const __half* __restrict__ t1, const __half* __restrict__ t2,
    const __half* __restrict__ t3, const __half* __restrict__ t4,
    float* __restrict__ ws2) {
  // XCD-chunked swizzle: 4096 blocks, 8 XCDs -> 512-block contiguous chunks.
  int bid = blockIdx.x;
  int swz = (bid & 7) * 512 + (bid >> 3);
  int i = swz * 256 + threadIdx.x;
  float4 r = pixrec[i];
  float gx = r.x * 2.0f - 1.0f;
  float gy = r.y * 2.0f - 1.0f;
  unsigned p = __float_as_uint(r.z);
  float m = r.w;
  float acc[CH];
#pragma unroll
  for (int c = 0; c < CH; ++c) acc[c] = 0.0f;
  sample_hwc16(t1, 1024, gx, gy, acc);
  sample_hwc16(t2, 512, gx, gy, acc);
  sample_hwc16(t3, 256, gx, gy, acc);
  sample_hwc16(t4, 128, gx, gy, acc);
  float4* w = (float4*)(ws2 + (size_t)p * CH);
#pragma unroll
  for (int c4 = 0; c4 < 4; ++c4)
    w[c4] = make_float4(acc[4 * c4 + 0] * m, acc[4 * c4 + 1] * m,
                        acc[4 * c4 + 2] * m, acc[4 * c4 + 3] * m);
}

// Unscatter ws2[p][16] -> out[B][C][Ho][Wo]. 4 pixels per thread -> float4 writes.
__global__ __launch_bounds__(256) void unscatter_kernel(
    const float* __restrict__ ws2, float* __restrict__ out) {
  int t = blockIdx.x * blockDim.x + threadIdx.x;  // [0, NPIX/4)
  int p0 = t * 4;
  int wo = p0 & 511, ho = (p0 >> 9) & 511, b = p0 >> 18;
  const float4* s = (const float4*)ws2;
  float4 v[4][4];
#pragma unroll
  for (int j = 0; j < 4; ++j) {
#pragma unroll
    for (int k = 0; k < 4; ++k) v[j][k] = s[(size_t)(p0 + j) * 4 + k];
  }
  size_t obase = (size_t)b * (CH * 262144) + (size_t)ho * 512 + wo;
#pragma unroll
  for (int k = 0; k < 4; ++k) {
#pragma unroll
    for (int c = 0; c < 4; ++c) {
      float4 o;
      o.x = (&v[0][k].x)[c];
      o.y = (&v[1][k].x)[c];
      o.z = (&v[2][k].x)[c];
      o.w = (&v[3][k].x)[c];
      *(float4*)(out + obase + (size_t)(4 * k + c) * 262144) = o;
    }
  }
}

// ---------------------------------------------------------------------------
// Fallback 1: direct output-order gather from fp16 interleaved (R1 kernel).
// ---------------------------------------------------------------------------
__global__ __launch_bounds__(256) void gather_hwc16_kernel(
    const float* __restrict__ x, const float* __restrict__ msk,
    const __half* __restrict__ t1, const __half* __restrict__ t2,
    const __half* __restrict__ t3, const __half* __restrict__ t4,
    float* __restrict__ out) {
  int p = blockIdx.x * blockDim.x + threadIdx.x;
  int wo = p & 511, ho = (p >> 9) & 511, b = p >> 18;
  float2 g = ((const float2*)x)[p];
  float gx = g.x * 2.0f - 1.0f;
  float gy = g.y * 2.0f - 1.0f;
  float m = msk[p];
  float acc[CH];
#pragma unroll
  for (int c = 0; c < CH; ++c) acc[c] = 0.0f;
  sample_hwc16(t1, 1024, gx, gy, acc);
  sample_hwc16(t2, 512, gx, gy, acc);
  sample_hwc16(t3, 256, gx, gy, acc);
  sample_hwc16(t4, 128, gx, gy, acc);
  size_t obase = (size_t)b * (CH * 262144) + (size_t)ho * 512 + wo;
#pragma unroll
  for (int c = 0; c < CH; ++c) out[obase + (size_t)c * 262144] = acc[c] * m;
}

// ---------------------------------------------------------------------------
// Fallback 2: direct gather from native [C, H, W] f32 layout.
// ---------------------------------------------------------------------------
__device__ __forceinline__ void sample_chw(const float* __restrict__ t, int W,
                                           float gx, float gy, float acc[CH]) {
  const float W1 = (float)(W - 1);
  float ix = (gx + 1.0f) * 0.5f * W1;
  float iy = (gy + 1.0f) * 0.5f * W1;
  float ix0f = floorf(ix), iy0f = floorf(iy);
  float wx1 = ix - ix0f, wy1 = iy - iy0f;
  float wx0 = 1.0f - wx1, wy0 = 1.0f - wy1;
  float ix1f = ix0f + 1.0f, iy1f = iy0f + 1.0f;
  float vx0 = (ix0f >= 0.0f && ix0f <= W1) ? 1.0f : 0.0f;
  float vx1 = (ix1f >= 0.0f && ix1f <= W1) ? 1.0f : 0.0f;
  float vy0 = (iy0f >= 0.0f && iy0f <= W1) ? 1.0f : 0.0f;
  float vy1 = (iy1f >= 0.0f && iy1f <= W1) ? 1.0f : 0.0f;
  int x0 = min(max((int)ix0f, 0), W - 1);
  int x1 = min(max((int)ix1f, 0), W - 1);
  int y0 = min(max((int)iy0f, 0), W - 1);
  int y1 = min(max((int)iy1f, 0), W - 1);
  float w00 = wy0 * wx0 * vy0 * vx0;
  float w01 = wy0 * wx1 * vy0 * vx1;
  float w10 = wy1 * wx0 * vy1 * vx0;
  float w11 = wy1 * wx1 * vy1 * vx1;
  size_t HW = (size_t)W * W;
  const float* b00 = t + (size_t)y0 * W + x0;
  const float* b01 = t + (size_t)y0 * W + x1;
  const float* b10 = t + (size_t)y1 * W + x0;
  const float* b11 = t + (size_t)y1 * W + x1;
#pragma unroll
  for (int c = 0; c < CH; ++c) {
    float v00 = b00[c * HW], v01 = b01[c * HW], v10 = b10[c * HW], v11 = b11[c * HW];
    acc[c] = fmaf(v00, w00, fmaf(v01, w01, fmaf(v10, w10, fmaf(v11, w11, acc[c]))));
  }
}

__global__ __launch_bounds__(256) void gather_chw_kernel(
    const float* __restrict__ x, const float* __restrict__ msk,
    const float* __restrict__ l1, const float* __restrict__ l2,
    const float* __restrict__ l3, const float* __restrict__ l4,
    float* __restrict__ out) {
  int p = blockIdx.x * blockDim.x + threadIdx.x;
  int wo = p & 511, ho = (p >> 9) & 511, b = p >> 18;
  float2 g = ((const float2*)x)[p];
  float gx = g.x * 2.0f - 1.0f;
  float gy = g.y * 2.0f - 1.0f;
  float m = msk[p];
  float acc[CH];
#pragma unroll
  for (int c = 0; c < CH; ++c) acc[c] = 0.0f;
  sample_chw(l1, 1024, gx, gy, acc);
  sample_chw(l2, 512, gx, gy, acc);
  sample_chw(l3, 256, gx, gy, acc);
  sample_chw(l4, 128, gx, gy, acc);
  size_t obase = (size_t)b * (CH * 262144) + (size_t)ho * 512 + wo;
#pragma unroll
  for (int c = 0; c < CH; ++c) out[obase + (size_t)c * 262144] = acc[c] * m;
}

extern "C" void kernel_launch(void* const* d_in, const int* in_sizes, int n_in,
                              void* d_out, int out_size, void* d_ws, size_t ws_size,
                              hipStream_t stream) {
  const float* x   = (const float*)d_in[0];
  const float* msk = (const float*)d_in[1];
  const float* l1  = (const float*)d_in[2];
  const float* l2  = (const float*)d_in[3];
  const float* l3  = (const float*)d_in[4];
  const float* l4  = (const float*)d_in[5];
  float* out = (float*)d_out;

  const size_t n_texel = 1048576 + 262144 + 65536 + 16384;  // 1392640
  const size_t tex_bytes = n_texel * CH * sizeof(__half);    // ~44.6 MB
  const size_t ws2_bytes = (size_t)NPIX * CH * sizeof(float);   // 64 MB
  const size_t rec_bytes = (size_t)NPIX * sizeof(float4);       // 16 MB
  const size_t cnt_bytes = (size_t)NBINS * sizeof(unsigned);    // 16 KB
  const size_t need_bin  = ws2_bytes + tex_bytes + rec_bytes + 2 * cnt_bytes;
  const size_t need_f16  = tex_bytes;

  if (ws_size >= need_bin) {
    char* base = (char*)d_ws;
    float*    ws2    = (float*)base;
    __half*   w1     = (__half*)(base + ws2_bytes);
    __half*   w2     = w1 + (size_t)1048576 * CH;
    __half*   w3     = w2 + (size_t)262144 * CH;
    __half*   w4     = w3 + (size_t)65536 * CH;
    float4*   pixrec = (float4*)(base + ws2_bytes + tex_bytes);
    unsigned* counts = (unsigned*)(base + ws2_bytes + tex_bytes + rec_bytes);
    unsigned* cursor = counts + NBINS;

    hipMemsetAsync(counts, 0, cnt_bytes, stream);
    interleave_fp16_kernel<<<1048576 / 256, 256, 0, stream>>>(l1, w1, 1048576);
    interleave_fp16_kernel<<<262144 / 256, 256, 0, stream>>>(l2, w2, 262144);
    interleave_fp16_kernel<<<65536 / 256, 256, 0, stream>>>(l3, w3, 65536);
    interleave_fp16_kernel<<<16384 / 256, 256, 0, stream>>>(l4, w4, 16384);
    count_kernel<<<NPIX / 256, 256, 0, stream>>>((const float2*)x, counts);
    scan_kernel<<<1, 1024, 0, stream>>>(counts, cursor);
    scatter_kernel<<<NPIX / 256, 256, 0, stream>>>((const float2*)x, msk, cursor, pixrec);
    gather_binned_kernel<<<NPIX / 256, 256, 0, stream>>>(pixrec, w1, w2, w3, w4, ws2);
    unscatter_kernel<<<NPIX / 4 / 256, 256, 0, stream>>>(ws2, out);
  } else if (ws_size >= need_f16) {
    __half* w1 = (__half*)d_ws;
    __half* w2 = w1 + (size_t)1048576 * CH;
    __half* w3 = w2 + (size_t)262144 * CH;
    __half* w4 = w3 + (size_t)65536 * CH;
    interleave_fp16_kernel<<<1048576 / 256, 256, 0, stream>>>(l1, w1, 1048576);
    interleave_fp16_kernel<<<262144 / 256, 256, 0, stream>>>(l2, w2, 262144);
    interleave_fp16_kernel<<<65536 / 256, 256, 0, stream>>>(l3, w3, 65536);
    interleave_fp16_kernel<<<16384 / 256, 256, 0, stream>>>(l4, w4, 16384);
    gather_hwc16_kernel<<<NPIX / 256, 256, 0, stream>>>(x, msk, w1, w2, w3, w4, out);
  } else {
    gather_chw_kernel<<<NPIX / 256, 256, 0, stream>>>(x, msk, l1, l2, l3, l4, out);
  }
}

// Round 4
// 159.217 us; speedup vs baseline: 1.7067x; 1.7067x over previous
//
#include <hip/hip_runtime.h>
#include <hip/hip_fp16.h>

#define CH 16
#define NPIX (4 * 512 * 512)
#define NBINS 4096        // 64x64 bins of 16x16 layer1 texels
#define NBLK_SORT 256     // sort-pass blocks
#define PPB (NPIX / NBLK_SORT)   // 4096 pixels per sort block
#define SEGS 16           // k-segments for the hist column scan

// ---------------------------------------------------------------------------
// Repack one pyramid layer from [C, H, W] f32 to [H, W, C] fp16 (interleaved).
// ---------------------------------------------------------------------------
__global__ __launch_bounds__(256) void interleave_fp16_kernel(
    const float* __restrict__ src, __half* __restrict__ dst, int HW) {
  int p = blockIdx.x * blockDim.x + threadIdx.x;
  if (p >= HW) return;
  union { __half h[CH]; uint4 u[2]; } pk;
#pragma unroll
  for (int c = 0; c < CH; ++c) pk.h[c] = __float2half(src[(size_t)c * HW + p]);
  uint4* d = (uint4*)(dst + (size_t)p * CH);
  d[0] = pk.u[0];
  d[1] = pk.u[1];
}

// ---------------------------------------------------------------------------
// One bilinear corner: load 16 fp16 channels (2x uint4), FMA into f32 acc.
// ---------------------------------------------------------------------------
__device__ __forceinline__ void corner_fma(const __half* __restrict__ t,
                                           size_t texel, float w, float acc[CH]) {
  const uint4* q = (const uint4*)(t + texel * CH);
  union { uint4 u; __half2 h[4]; } a, b;
  a.u = q[0];
  b.u = q[1];
#pragma unroll
  for (int i = 0; i < 4; ++i) {
    float2 f = __half22float2(a.h[i]);
    acc[2 * i + 0] = fmaf(f.x, w, acc[2 * i + 0]);
    acc[2 * i + 1] = fmaf(f.y, w, acc[2 * i + 1]);
  }
#pragma unroll
  for (int i = 0; i < 4; ++i) {
    float2 f = __half22float2(b.h[i]);
    acc[8 + 2 * i + 0] = fmaf(f.x, w, acc[8 + 2 * i + 0]);
    acc[8 + 2 * i + 1] = fmaf(f.y, w, acc[8 + 2 * i + 1]);
  }
}

// Bilinear sample of one interleaved fp16 [H, W, C] layer into f32 acc[CH].
__device__ __forceinline__ void sample_hwc16(const __half* __restrict__ t, int W,
                                             float gx, float gy, float acc[CH]) {
  const float W1 = (float)(W - 1);
  float ix = (gx + 1.0f) * 0.5f * W1;
  float iy = (gy + 1.0f) * 0.5f * W1;
  float ix0f = floorf(ix), iy0f = floorf(iy);
  float wx1 = ix - ix0f, wy1 = iy - iy0f;
  float wx0 = 1.0f - wx1, wy0 = 1.0f - wy1;
  float ix1f = ix0f + 1.0f, iy1f = iy0f + 1.0f;
  float vx0 = (ix0f >= 0.0f && ix0f <= W1) ? 1.0f : 0.0f;
  float vx1 = (ix1f >= 0.0f && ix1f <= W1) ? 1.0f : 0.0f;
  float vy0 = (iy0f >= 0.0f && iy0f <= W1) ? 1.0f : 0.0f;
  float vy1 = (iy1f >= 0.0f && iy1f <= W1) ? 1.0f : 0.0f;
  int x0 = min(max((int)ix0f, 0), W - 1);
  int x1 = min(max((int)ix1f, 0), W - 1);
  int y0 = min(max((int)iy0f, 0), W - 1);
  int y1 = min(max((int)iy1f, 0), W - 1);
  float w00 = wy0 * wx0 * vy0 * vx0;
  float w01 = wy0 * wx1 * vy0 * vx1;
  float w10 = wy1 * wx0 * vy1 * vx0;
  float w11 = wy1 * wx1 * vy1 * vx1;
  corner_fma(t, (size_t)y0 * W + x0, w00, acc);
  corner_fma(t, (size_t)y0 * W + x1, w01, acc);
  corner_fma(t, (size_t)y1 * W + x0, w10, acc);
  corner_fma(t, (size_t)y1 * W + x1, w11, acc);
}

// ---------------------------------------------------------------------------
// Binning: bin = 16x16-texel tile at layer1 (1024^2) resolution.
// ---------------------------------------------------------------------------
__device__ __forceinline__ int bin_of(float xv, float yv) {
  int bx = min(max((int)(xv * 1023.0f), 0), 1023) >> 4;
  int by = min(max((int)(yv * 1023.0f), 0), 1023) >> 4;
  return (by << 6) + bx;
}

// Pass A: per-sort-block LDS histogram -> hist[blk][NBINS]. No global atomics.
__global__ __launch_bounds__(256) void hist_kernel(
    const float2* __restrict__ x, unsigned* __restrict__ hist) {
  __shared__ unsigned h[NBINS];
  int tid = threadIdx.x, blk = blockIdx.x;
#pragma unroll
  for (int i = 0; i < NBINS / 256; ++i) h[i * 256 + tid] = 0;
  __syncthreads();
  int base = blk * PPB;
#pragma unroll 4
  for (int c = 0; c < PPB / 256; ++c) {
    float2 g = x[base + c * 256 + tid];
    atomicAdd(&h[bin_of(g.x, g.y)], 1u);
  }
  __syncthreads();
#pragma unroll
  for (int i = 0; i < NBINS / 256; ++i)
    hist[(size_t)blk * NBINS + i * 256 + tid] = h[i * 256 + tid];
}

// Pass B1: per-segment column sums. partial[s][bin] = sum_{k in seg s} hist[k][bin].
__global__ __launch_bounds__(256) void segsum_kernel(
    const unsigned* __restrict__ hist, unsigned* __restrict__ partial) {
  int gid = blockIdx.x * 256 + threadIdx.x;  // SEGS*NBINS
  int s = gid >> 12, bin = gid & (NBINS - 1);
  unsigned sum = 0;
#pragma unroll
  for (int k = 0; k < NBLK_SORT / SEGS; ++k)
    sum += hist[(size_t)(s * (NBLK_SORT / SEGS) + k) * NBINS + bin];
  partial[gid] = sum;
}

// Pass B2: per-bin exclusive scan over segments; totals[bin] = column total.
__global__ __launch_bounds__(256) void segscan_kernel(
    unsigned* __restrict__ partial, unsigned* __restrict__ totals) {
  int bin = blockIdx.x * 256 + threadIdx.x;
  unsigned run = 0;
#pragma unroll
  for (int s = 0; s < SEGS; ++s) {
    unsigned v = partial[s * NBINS + bin];
    partial[s * NBINS + bin] = run;
    run += v;
  }
  totals[bin] = run;
}

// Pass B3: exclusive scan of 4096 totals -> binbase (one block, 1024 threads).
__global__ __launch_bounds__(1024) void scan_kernel(
    const unsigned* __restrict__ counts, unsigned* __restrict__ cursor) {
  __shared__ unsigned part[1024];
  int t = threadIdx.x;
  unsigned c0 = counts[4 * t + 0], c1 = counts[4 * t + 1];
  unsigned c2 = counts[4 * t + 2], c3 = counts[4 * t + 3];
  part[t] = c0 + c1 + c2 + c3;
  __syncthreads();
  for (int off = 1; off < 1024; off <<= 1) {
    unsigned v = (t >= off) ? part[t - off] : 0u;
    __syncthreads();
    part[t] += v;
    __syncthreads();
  }
  unsigned base = (t > 0) ? part[t - 1] : 0u;  // exclusive
  cursor[4 * t + 0] = base;
  cursor[4 * t + 1] = base + c0;
  cursor[4 * t + 2] = base + c0 + c1;
  cursor[4 * t + 3] = base + c0 + c1 + c2;
}

// Pass B4: convert hist[k][bin] counts -> global exclusive base for (k, bin).
__global__ __launch_bounds__(256) void colscan_kernel(
    unsigned* __restrict__ hist, const unsigned* __restrict__ partial,
    const unsigned* __restrict__ binbase) {
  int gid = blockIdx.x * 256 + threadIdx.x;
  int s = gid >> 12, bin = gid & (NBINS - 1);
  unsigned run = partial[s * NBINS + bin] + binbase[bin];
#pragma unroll
  for (int k = 0; k < NBLK_SORT / SEGS; ++k) {
    size_t idx = (size_t)(s * (NBLK_SORT / SEGS) + k) * NBINS + bin;
    unsigned v = hist[idx];
    hist[idx] = run;
    run += v;
  }
}

// Pass C: scatter with LDS cursors seeded from hist bases. No global atomics.
__global__ __launch_bounds__(256) void scatter2_kernel(
    const float2* __restrict__ x, const float* __restrict__ msk,
    const unsigned* __restrict__ hist, float4* __restrict__ pixrec) {
  __shared__ unsigned cur[NBINS];
  int tid = threadIdx.x, blk = blockIdx.x;
#pragma unroll
  for (int i = 0; i < NBINS / 256; ++i)
    cur[i * 256 + tid] = hist[(size_t)blk * NBINS + i * 256 + tid];
  __syncthreads();
  int base = blk * PPB;
#pragma unroll 4
  for (int c = 0; c < PPB / 256; ++c) {
    int p = base + c * 256 + tid;
    float2 g = x[p];
    float m = msk[p];
    unsigned i = atomicAdd(&cur[bin_of(g.x, g.y)], 1u);
    pixrec[i] = make_float4(g.x, g.y, __uint_as_float((unsigned)p), m);
  }
}

// Gather in bin (texture-locality) order; write pixel-major staging ws2[p][16].
__global__ __launch_bounds__(256) void gather_binned_kernel(
    const float4* __restrict__ pixrec,
    const __half* __restrict__ t1, const __half* __restrict__ t2,
    const __half* __restrict__ t3, const __half* __restrict__ t4,
    float* __restrict__ ws2) {
  // XCD-chunked swizzle: 4096 blocks, 8 XCDs -> 512-block contiguous chunks.
  int bid = blockIdx.x;
  int swz = (bid & 7) * 512 + (bid >> 3);
  int i = swz * 256 + threadIdx.x;
  float4 r = pixrec[i];
  float gx = r.x * 2.0f - 1.0f;
  float gy = r.y * 2.0f - 1.0f;
  unsigned p = __float_as_uint(r.z);
  float m = r.w;
  float acc[CH];
#pragma unroll
  for (int c = 0; c < CH; ++c) acc[c] = 0.0f;
  sample_hwc16(t1, 1024, gx, gy, acc);
  sample_hwc16(t2, 512, gx, gy, acc);
  sample_hwc16(t3, 256, gx, gy, acc);
  sample_hwc16(t4, 128, gx, gy, acc);
  float4* w = (float4*)(ws2 + (size_t)p * CH);
#pragma unroll
  for (int c4 = 0; c4 < 4; ++c4)
    w[c4] = make_float4(acc[4 * c4 + 0] * m, acc[4 * c4 + 1] * m,
                        acc[4 * c4 + 2] * m, acc[4 * c4 + 3] * m);
}

// Unscatter ws2[p][16] -> out[B][C][Ho][Wo]. 4 pixels per thread -> float4 writes.
__global__ __launch_bounds__(256) void unscatter_kernel(
    const float* __restrict__ ws2, float* __restrict__ out) {
  int t = blockIdx.x * blockDim.x + threadIdx.x;  // [0, NPIX/4)
  int p0 = t * 4;
  int wo = p0 & 511, ho = (p0 >> 9) & 511, b = p0 >> 18;
  const float4* s = (const float4*)ws2;
  float4 v[4][4];
#pragma unroll
  for (int j = 0; j < 4; ++j) {
#pragma unroll
    for (int k = 0; k < 4; ++k) v[j][k] = s[(size_t)(p0 + j) * 4 + k];
  }
  size_t obase = (size_t)b * (CH * 262144) + (size_t)ho * 512 + wo;
#pragma unroll
  for (int k = 0; k < 4; ++k) {
#pragma unroll
    for (int c = 0; c < 4; ++c) {
      float4 o;
      o.x = (&v[0][k].x)[c];
      o.y = (&v[1][k].x)[c];
      o.z = (&v[2][k].x)[c];
      o.w = (&v[3][k].x)[c];
      *(float4*)(out + obase + (size_t)(4 * k + c) * 262144) = o;
    }
  }
}

// ---------------------------------------------------------------------------
// Fallback 1: direct output-order gather from fp16 interleaved (R1 kernel).
// ---------------------------------------------------------------------------
__global__ __launch_bounds__(256) void gather_hwc16_kernel(
    const float* __restrict__ x, const float* __restrict__ msk,
    const __half* __restrict__ t1, const __half* __restrict__ t2,
    const __half* __restrict__ t3, const __half* __restrict__ t4,
    float* __restrict__ out) {
  int p = blockIdx.x * blockDim.x + threadIdx.x;
  int wo = p & 511, ho = (p >> 9) & 511, b = p >> 18;
  float2 g = ((const float2*)x)[p];
  float gx = g.x * 2.0f - 1.0f;
  float gy = g.y * 2.0f - 1.0f;
  float m = msk[p];
  float acc[CH];
#pragma unroll
  for (int c = 0; c < CH; ++c) acc[c] = 0.0f;
  sample_hwc16(t1, 1024, gx, gy, acc);
  sample_hwc16(t2, 512, gx, gy, acc);
  sample_hwc16(t3, 256, gx, gy, acc);
  sample_hwc16(t4, 128, gx, gy, acc);
  size_t obase = (size_t)b * (CH * 262144) + (size_t)ho * 512 + wo;
#pragma unroll
  for (int c = 0; c < CH; ++c) out[obase + (size_t)c * 262144] = acc[c] * m;
}

// ---------------------------------------------------------------------------
// Fallback 2: direct gather from native [C, H, W] f32 layout.
// ---------------------------------------------------------------------------
__device__ __forceinline__ void sample_chw(const float* __restrict__ t, int W,
                                           float gx, float gy, float acc[CH]) {
  const float W1 = (float)(W - 1);
  float ix = (gx + 1.0f) * 0.5f * W1;
  float iy = (gy + 1.0f) * 0.5f * W1;
  float ix0f = floorf(ix), iy0f = floorf(iy);
  float wx1 = ix - ix0f, wy1 = iy - iy0f;
  float wx0 = 1.0f - wx1, wy0 = 1.0f - wy1;
  float ix1f = ix0f + 1.0f, iy1f = iy0f + 1.0f;
  float vx0 = (ix0f >= 0.0f && ix0f <= W1) ? 1.0f : 0.0f;
  float vx1 = (ix1f >= 0.0f && ix1f <= W1) ? 1.0f : 0.0f;
  float vy0 = (iy0f >= 0.0f && iy0f <= W1) ? 1.0f : 0.0f;
  float vy1 = (iy1f >= 0.0f && iy1f <= W1) ? 1.0f : 0.0f;
  int x0 = min(max((int)ix0f, 0), W - 1);
  int x1 = min(max((int)ix1f, 0), W - 1);
  int y0 = min(max((int)iy0f, 0), W - 1);
  int y1 = min(max((int)iy1f, 0), W - 1);
  float w00 = wy0 * wx0 * vy0 * vx0;
  float w01 = wy0 * wx1 * vy0 * vx1;
  float w10 = wy1 * wx0 * vy1 * vx0;
  float w11 = wy1 * wx1 * vy1 * vx1;
  size_t HW = (size_t)W * W;
  const float* b00 = t + (size_t)y0 * W + x0;
  const float* b01 = t + (size_t)y0 * W + x1;
  const float* b10 = t + (size_t)y1 * W + x0;
  const float* b11 = t + (size_t)y1 * W + x1;
#pragma unroll
  for (int c = 0; c < CH; ++c) {
    float v00 = b00[c * HW], v01 = b01[c * HW], v10 = b10[c * HW], v11 = b11[c * HW];
    acc[c] = fmaf(v00, w00, fmaf(v01, w01, fmaf(v10, w10, fmaf(v11, w11, acc[c]))));
  }
}

__global__ __launch_bounds__(256) void gather_chw_kernel(
    const float* __restrict__ x, const float* __restrict__ msk,
    const float* __restrict__ l1, const float* __restrict__ l2,
    const float* __restrict__ l3, const float* __restrict__ l4,
    float* __restrict__ out) {
  int p = blockIdx.x * blockDim.x + threadIdx.x;
  int wo = p & 511, ho = (p >> 9) & 511, b = p >> 18;
  float2 g = ((const float2*)x)[p];
  float gx = g.x * 2.0f - 1.0f;
  float gy = g.y * 2.0f - 1.0f;
  float m = msk[p];
  float acc[CH];
#pragma unroll
  for (int c = 0; c < CH; ++c) acc[c] = 0.0f;
  sample_chw(l1, 1024, gx, gy, acc);
  sample_chw(l2, 512, gx, gy, acc);
  sample_chw(l3, 256, gx, gy, acc);
  sample_chw(l4, 128, gx, gy, acc);
  size_t obase = (size_t)b * (CH * 262144) + (size_t)ho * 512 + wo;
#pragma unroll
  for (int c = 0; c < CH; ++c) out[obase + (size_t)c * 262144] = acc[c] * m;
}

extern "C" void kernel_launch(void* const* d_in, const int* in_sizes, int n_in,
                              void* d_out, int out_size, void* d_ws, size_t ws_size,
                              hipStream_t stream) {
  const float* x   = (const float*)d_in[0];
  const float* msk = (const float*)d_in[1];
  const float* l1  = (const float*)d_in[2];
  const float* l2  = (const float*)d_in[3];
  const float* l3  = (const float*)d_in[4];
  const float* l4  = (const float*)d_in[5];
  float* out = (float*)d_out;

  const size_t n_texel = 1048576 + 262144 + 65536 + 16384;     // 1392640
  const size_t tex_bytes = n_texel * CH * sizeof(__half);       // ~44.6 MB
  const size_t ws2_bytes = (size_t)NPIX * CH * sizeof(float);   // 64 MB
  const size_t rec_bytes = (size_t)NPIX * sizeof(float4);       // 16 MB
  const size_t need_bin  = ws2_bytes + tex_bytes + rec_bytes;
  const size_t need_f16  = tex_bytes;

  if (ws_size >= need_bin) {
    char* base = (char*)d_ws;
    float*  ws2    = (float*)base;
    __half* w1     = (__half*)(base + ws2_bytes);
    __half* w2     = w1 + (size_t)1048576 * CH;
    __half* w3     = w2 + (size_t)262144 * CH;
    __half* w4     = w3 + (size_t)65536 * CH;
    float4* pixrec = (float4*)(base + ws2_bytes + tex_bytes);
    // Sort metadata aliases into ws2 (dead once gather starts writing ws2):
    unsigned* hist    = (unsigned*)base;                          // 4 MB
    unsigned* partial = hist + (size_t)NBLK_SORT * NBINS;         // 256 KB
    unsigned* totals  = partial + (size_t)SEGS * NBINS;           // 16 KB
    unsigned* binbase = totals + NBINS;                           // 16 KB

    interleave_fp16_kernel<<<1048576 / 256, 256, 0, stream>>>(l1, w1, 1048576);
    interleave_fp16_kernel<<<262144 / 256, 256, 0, stream>>>(l2, w2, 262144);
    interleave_fp16_kernel<<<65536 / 256, 256, 0, stream>>>(l3, w3, 65536);
    interleave_fp16_kernel<<<16384 / 256, 256, 0, stream>>>(l4, w4, 16384);
    hist_kernel<<<NBLK_SORT, 256, 0, stream>>>((const float2*)x, hist);
    segsum_kernel<<<SEGS * NBINS / 256, 256, 0, stream>>>(hist, partial);
    segscan_kernel<<<NBINS / 256, 256, 0, stream>>>(partial, totals);
    scan_kernel<<<1, 1024, 0, stream>>>(totals, binbase);
    colscan_kernel<<<SEGS * NBINS / 256, 256, 0, stream>>>(hist, partial, binbase);
    scatter2_kernel<<<NBLK_SORT, 256, 0, stream>>>((const float2*)x, msk, hist, pixrec);
    gather_binned_kernel<<<NPIX / 256, 256, 0, stream>>>(pixrec, w1, w2, w3, w4, ws2);
    unscatter_kernel<<<NPIX / 4 / 256, 256, 0, stream>>>(ws2, out);
  } else if (ws_size >= need_f16) {
    __half* w1 = (__half*)d_ws;
    __half* w2 = w1 + (size_t)1048576 * CH;
    __half* w3 = w2 + (size_t)262144 * CH;
    __half* w4 = w3 + (size_t)65536 * CH;
    interleave_fp16_kernel<<<1048576 / 256, 256, 0, stream>>>(l1, w1, 1048576);
    interleave_fp16_kernel<<<262144 / 256, 256, 0, stream>>>(l2, w2, 262144);
    interleave_fp16_kernel<<<65536 / 256, 256, 0, stream>>>(l3, w3, 65536);
    interleave_fp16_kernel<<<16384 / 256, 256, 0, stream>>>(l4, w4, 16384);
    gather_hwc16_kernel<<<NPIX / 256, 256, 0, stream>>>(x, msk, w1, w2, w3, w4, out);
  } else {
    gather_chw_kernel<<<NPIX / 256, 256, 0, stream>>>(x, msk, l1, l2, l3, l4, out);
  }
}

// Round 6
// 124.816 us; speedup vs baseline: 2.1771x; 1.2756x over previous
//
#include <hip/hip_runtime.h>
#include <hip/hip_fp16.h>

#define CH 16
#define NPIX (4 * 512 * 512)
#define NBINS 4096        // 64x64 bins of 16x16 layer1 texels
#define NBLK_SORT 256     // sort-pass blocks
#define PPB (NPIX / NBLK_SORT)   // 4096 pixels per sort block
#define SEGS 16           // k-segments for the hist column scan

// ---------------------------------------------------------------------------
// Fused repack: all 4 pyramid layers [C,H,W] f32 -> [H,W,C] fp16 interleaved.
// Layer range boundaries are all multiples of 256 -> no divergent blocks.
// ---------------------------------------------------------------------------
__global__ __launch_bounds__(256) void interleave_all_kernel(
    const float* __restrict__ l1, const float* __restrict__ l2,
    const float* __restrict__ l3, const float* __restrict__ l4,
    __half* __restrict__ w1, __half* __restrict__ w2,
    __half* __restrict__ w3, __half* __restrict__ w4) {
  int g = blockIdx.x * blockDim.x + threadIdx.x;
  const float* src; __half* dst; int HW, p;
  if (g < 1048576)      { src = l1; dst = w1; HW = 1048576; p = g; }
  else if (g < 1310720) { src = l2; dst = w2; HW = 262144;  p = g - 1048576; }
  else if (g < 1376256) { src = l3; dst = w3; HW = 65536;   p = g - 1310720; }
  else                  { src = l4; dst = w4; HW = 16384;   p = g - 1376256; }
  union { __half h[CH]; uint4 u[2]; } pk;
#pragma unroll
  for (int c = 0; c < CH; ++c) pk.h[c] = __float2half(src[(size_t)c * HW + p]);
  uint4* d = (uint4*)(dst + (size_t)p * CH);
  d[0] = pk.u[0];
  d[1] = pk.u[1];
}

// ---------------------------------------------------------------------------
// One bilinear corner: load 16 fp16 channels (2x uint4), FMA into f32 acc.
// ---------------------------------------------------------------------------
__device__ __forceinline__ void corner_fma(const __half* __restrict__ t,
                                           size_t texel, float w, float acc[CH]) {
  const uint4* q = (const uint4*)(t + texel * CH);
  union { uint4 u; __half2 h[4]; } a, b;
  a.u = q[0];
  b.u = q[1];
#pragma unroll
  for (int i = 0; i < 4; ++i) {
    float2 f = __half22float2(a.h[i]);
    acc[2 * i + 0] = fmaf(f.x, w, acc[2 * i + 0]);
    acc[2 * i + 1] = fmaf(f.y, w, acc[2 * i + 1]);
  }
#pragma unroll
  for (int i = 0; i < 4; ++i) {
    float2 f = __half22float2(b.h[i]);
    acc[8 + 2 * i + 0] = fmaf(f.x, w, acc[8 + 2 * i + 0]);
    acc[8 + 2 * i + 1] = fmaf(f.y, w, acc[8 + 2 * i + 1]);
  }
}

// Bilinear sample of one interleaved fp16 [H, W, C] layer into f32 acc[CH].
__device__ __forceinline__ void sample_hwc16(const __half* __restrict__ t, int W,
                                             float gx, float gy, float acc[CH]) {
  const float W1 = (float)(W - 1);
  float ix = (gx + 1.0f) * 0.5f * W1;
  float iy = (gy + 1.0f) * 0.5f * W1;
  float ix0f = floorf(ix), iy0f = floorf(iy);
  float wx1 = ix - ix0f, wy1 = iy - iy0f;
  float wx0 = 1.0f - wx1, wy0 = 1.0f - wy1;
  float ix1f = ix0f + 1.0f, iy1f = iy0f + 1.0f;
  float vx0 = (ix0f >= 0.0f && ix0f <= W1) ? 1.0f : 0.0f;
  float vx1 = (ix1f >= 0.0f && ix1f <= W1) ? 1.0f : 0.0f;
  float vy0 = (iy0f >= 0.0f && iy0f <= W1) ? 1.0f : 0.0f;
  float vy1 = (iy1f >= 0.0f && iy1f <= W1) ? 1.0f : 0.0f;
  int x0 = min(max((int)ix0f, 0), W - 1);
  int x1 = min(max((int)ix1f, 0), W - 1);
  int y0 = min(max((int)iy0f, 0), W - 1);
  int y1 = min(max((int)iy1f, 0), W - 1);
  float w00 = wy0 * wx0 * vy0 * vx0;
  float w01 = wy0 * wx1 * vy0 * vx1;
  float w10 = wy1 * wx0 * vy1 * vx0;
  float w11 = wy1 * wx1 * vy1 * vx1;
  corner_fma(t, (size_t)y0 * W + x0, w00, acc);
  corner_fma(t, (size_t)y0 * W + x1, w01, acc);
  corner_fma(t, (size_t)y1 * W + x0, w10, acc);
  corner_fma(t, (size_t)y1 * W + x1, w11, acc);
}

// ---------------------------------------------------------------------------
// Binning: bin = 16x16-texel tile at layer1 (1024^2) resolution.
// ---------------------------------------------------------------------------
__device__ __forceinline__ int bin_of(float xv, float yv) {
  int bx = min(max((int)(xv * 1023.0f), 0), 1023) >> 4;
  int by = min(max((int)(yv * 1023.0f), 0), 1023) >> 4;
  return (by << 6) + bx;
}

// Pass A: per-sort-block LDS histogram -> hist[blk][NBINS]. No global atomics.
__global__ __launch_bounds__(256) void hist_kernel(
    const float2* __restrict__ x, unsigned* __restrict__ hist) {
  __shared__ unsigned h[NBINS];
  int tid = threadIdx.x, blk = blockIdx.x;
#pragma unroll
  for (int i = 0; i < NBINS / 256; ++i) h[i * 256 + tid] = 0;
  __syncthreads();
  int base = blk * PPB;
#pragma unroll 4
  for (int c = 0; c < PPB / 256; ++c) {
    float2 g = x[base + c * 256 + tid];
    atomicAdd(&h[bin_of(g.x, g.y)], 1u);
  }
  __syncthreads();
#pragma unroll
  for (int i = 0; i < NBINS / 256; ++i)
    hist[(size_t)blk * NBINS + i * 256 + tid] = h[i * 256 + tid];
}

// Pass B1: per-segment column sums.
__global__ __launch_bounds__(256) void segsum_kernel(
    const unsigned* __restrict__ hist, unsigned* __restrict__ partial) {
  int gid = blockIdx.x * 256 + threadIdx.x;  // SEGS*NBINS
  int s = gid >> 12, bin = gid & (NBINS - 1);
  unsigned sum = 0;
#pragma unroll
  for (int k = 0; k < NBLK_SORT / SEGS; ++k)
    sum += hist[(size_t)(s * (NBLK_SORT / SEGS) + k) * NBINS + bin];
  partial[gid] = sum;
}

// Pass B2: per-bin exclusive scan over segments; totals[bin] = column total.
__global__ __launch_bounds__(256) void segscan_kernel(
    unsigned* __restrict__ partial, unsigned* __restrict__ totals) {
  int bin = blockIdx.x * 256 + threadIdx.x;
  unsigned run = 0;
#pragma unroll
  for (int s = 0; s < SEGS; ++s) {
    unsigned v = partial[s * NBINS + bin];
    partial[s * NBINS + bin] = run;
    run += v;
  }
  totals[bin] = run;
}

// Pass B3: exclusive scan of 4096 totals -> binbase (one block, 1024 threads).
__global__ __launch_bounds__(1024) void scan_kernel(
    const unsigned* __restrict__ counts, unsigned* __restrict__ cursor) {
  __shared__ unsigned part[1024];
  int t = threadIdx.x;
  unsigned c0 = counts[4 * t + 0], c1 = counts[4 * t + 1];
  unsigned c2 = counts[4 * t + 2], c3 = counts[4 * t + 3];
  part[t] = c0 + c1 + c2 + c3;
  __syncthreads();
  for (int off = 1; off < 1024; off <<= 1) {
    unsigned v = (t >= off) ? part[t - off] : 0u;
    __syncthreads();
    part[t] += v;
    __syncthreads();
  }
  unsigned base = (t > 0) ? part[t - 1] : 0u;  // exclusive
  cursor[4 * t + 0] = base;
  cursor[4 * t + 1] = base + c0;
  cursor[4 * t + 2] = base + c0 + c1;
  cursor[4 * t + 3] = base + c0 + c1 + c2;
}

// Pass B4: convert hist[k][bin] counts -> global exclusive base for (k, bin).
__global__ __launch_bounds__(256) void colscan_kernel(
    unsigned* __restrict__ hist, const unsigned* __restrict__ partial,
    const unsigned* __restrict__ binbase) {
  int gid = blockIdx.x * 256 + threadIdx.x;
  int s = gid >> 12, bin = gid & (NBINS - 1);
  unsigned run = partial[s * NBINS + bin] + binbase[bin];
#pragma unroll
  for (int k = 0; k < NBLK_SORT / SEGS; ++k) {
    size_t idx = (size_t)(s * (NBLK_SORT / SEGS) + k) * NBINS + bin;
    unsigned v = hist[idx];
    hist[idx] = run;
    run += v;
  }
}

// Pass C: scatter with LDS cursors seeded from hist bases. No global atomics.
__global__ __launch_bounds__(256) void scatter2_kernel(
    const float2* __restrict__ x, const float* __restrict__ msk,
    const unsigned* __restrict__ hist, float4* __restrict__ pixrec) {
  __shared__ unsigned cur[NBINS];
  int tid = threadIdx.x, blk = blockIdx.x;
#pragma unroll
  for (int i = 0; i < NBINS / 256; ++i)
    cur[i * 256 + tid] = hist[(size_t)blk * NBINS + i * 256 + tid];
  __syncthreads();
  int base = blk * PPB;
#pragma unroll 4
  for (int c = 0; c < PPB / 256; ++c) {
    int p = base + c * 256 + tid;
    float2 g = x[p];
    float m = msk[p];
    unsigned i = atomicAdd(&cur[bin_of(g.x, g.y)], 1u);
    pixrec[i] = make_float4(g.x, g.y, __uint_as_float((unsigned)p), m);
  }
}

// 4-bit -> even-bit spread for Morton keys.
__device__ __forceinline__ unsigned spread4(unsigned v) {
  v = (v | (v << 2)) & 0x33u;
  v = (v | (v << 1)) & 0x55u;
  return v;
}

// Gather in bin order with an in-block Morton sub-sort; write fp16 staging.
__global__ __launch_bounds__(256) void gather_binned_kernel(
    const float4* __restrict__ pixrec,
    const __half* __restrict__ t1, const __half* __restrict__ t2,
    const __half* __restrict__ t3, const __half* __restrict__ t4,
    __half* __restrict__ ws2) {
  __shared__ float4 srec[256];
  __shared__ unsigned scnt[256];
  __shared__ unsigned sbase[256];
  int tid = threadIdx.x;
  // XCD-chunked swizzle: 4096 blocks, 8 XCDs -> 512-block contiguous chunks.
  int bid = blockIdx.x;
  int swz = (bid & 7) * 512 + (bid >> 3);
  float4 r = pixrec[swz * 256 + tid];

  // --- Morton counting sort by texel position within the 16x16 bin ---
  int txq = min(max((int)(r.x * 1023.0f), 0), 1023) & 15;
  int tyq = min(max((int)(r.y * 1023.0f), 0), 1023) & 15;
  unsigned key = spread4((unsigned)txq) | (spread4((unsigned)tyq) << 1);
  scnt[tid] = 0;
  __syncthreads();
  unsigned rank = atomicAdd(&scnt[key], 1u);
  __syncthreads();
  sbase[tid] = scnt[tid];
  __syncthreads();
  for (int off = 1; off < 256; off <<= 1) {
    unsigned v = (tid >= off) ? sbase[tid - off] : 0u;
    __syncthreads();
    sbase[tid] += v;
    __syncthreads();
  }
  unsigned pos = sbase[key] - scnt[key] + rank;  // exclusive base + rank
  srec[pos] = r;
  __syncthreads();
  r = srec[tid];

  float gx = r.x * 2.0f - 1.0f;
  float gy = r.y * 2.0f - 1.0f;
  unsigned p = __float_as_uint(r.z);
  float m = r.w;
  float acc[CH];
#pragma unroll
  for (int c = 0; c < CH; ++c) acc[c] = 0.0f;
  sample_hwc16(t1, 1024, gx, gy, acc);
  sample_hwc16(t2, 512, gx, gy, acc);
  sample_hwc16(t3, 256, gx, gy, acc);
  sample_hwc16(t4, 128, gx, gy, acc);
  union { __half2 h[8]; uint4 u[2]; } o;
#pragma unroll
  for (int c = 0; c < 8; ++c)
    o.h[c] = __floats2half2_rn(acc[2 * c] * m, acc[2 * c + 1] * m);
  uint4* w = (uint4*)(ws2 + (size_t)p * CH);
  w[0] = o.u[0];
  w[1] = o.u[1];
}

// Unscatter fp16 ws2[p][16] -> f32 out[B][C][Ho][Wo]. 4 pixels per thread.
__global__ __launch_bounds__(256) void unscatter16_kernel(
    const __half* __restrict__ ws2, float* __restrict__ out) {
  int t = blockIdx.x * blockDim.x + threadIdx.x;  // [0, NPIX/4)
  int p0 = t * 4;
  int wo = p0 & 511, ho = (p0 >> 9) & 511, b = p0 >> 18;
  const uint4* s = (const uint4*)ws2;
  union { uint4 u[2]; __half2 h[8]; } v[4];
#pragma unroll
  for (int j = 0; j < 4; ++j) {
    v[j].u[0] = s[(size_t)(p0 + j) * 2 + 0];
    v[j].u[1] = s[(size_t)(p0 + j) * 2 + 1];
  }
  size_t obase = (size_t)b * (CH * 262144) + (size_t)ho * 512 + wo;
#pragma unroll
  for (int ch = 0; ch < CH; ++ch) {
    float4 o;
    o.x = __half2float(((ch & 1) ? __high2half(v[0].h[ch >> 1]) : __low2half(v[0].h[ch >> 1])));
    o.y = __half2float(((ch & 1) ? __high2half(v[1].h[ch >> 1]) : __low2half(v[1].h[ch >> 1])));
    o.z = __half2float(((ch & 1) ? __high2half(v[2].h[ch >> 1]) : __low2half(v[2].h[ch >> 1])));
    o.w = __half2float(((ch & 1) ? __high2half(v[3].h[ch >> 1]) : __low2half(v[3].h[ch >> 1])));
    *(float4*)(out + obase + (size_t)ch * 262144) = o;
  }
}

// ---------------------------------------------------------------------------
// Fallback 1: direct output-order gather from fp16 interleaved (R1 kernel).
// ---------------------------------------------------------------------------
__global__ __launch_bounds__(256) void gather_hwc16_kernel(
    const float* __restrict__ x, const float* __restrict__ msk,
    const __half* __restrict__ t1, const __half* __restrict__ t2,
    const __half* __restrict__ t3, const __half* __restrict__ t4,
    float* __restrict__ out) {
  int p = blockIdx.x * blockDim.x + threadIdx.x;
  int wo = p & 511, ho = (p >> 9) & 511, b = p >> 18;
  float2 g = ((const float2*)x)[p];
  float gx = g.x * 2.0f - 1.0f;
  float gy = g.y * 2.0f - 1.0f;
  float m = msk[p];
  float acc[CH];
#pragma unroll
  for (int c = 0; c < CH; ++c) acc[c] = 0.0f;
  sample_hwc16(t1, 1024, gx, gy, acc);
  sample_hwc16(t2, 512, gx, gy, acc);
  sample_hwc16(t3, 256, gx, gy, acc);
  sample_hwc16(t4, 128, gx, gy, acc);
  size_t obase = (size_t)b * (CH * 262144) + (size_t)ho * 512 + wo;
#pragma unroll
  for (int c = 0; c < CH; ++c) out[obase + (size_t)c * 262144] = acc[c] * m;
}

// ---------------------------------------------------------------------------
// Fallback 2: direct gather from native [C, H, W] f32 layout.
// ---------------------------------------------------------------------------
__device__ __forceinline__ void sample_chw(const float* __restrict__ t, int W,
                                           float gx, float gy, float acc[CH]) {
  const float W1 = (float)(W - 1);
  float ix = (gx + 1.0f) * 0.5f * W1;
  float iy = (gy + 1.0f) * 0.5f * W1;
  float ix0f = floorf(ix), iy0f = floorf(iy);
  float wx1 = ix - ix0f, wy1 = iy - iy0f;
  float wx0 = 1.0f - wx1, wy0 = 1.0f - wy1;
  float ix1f = ix0f + 1.0f, iy1f = iy0f + 1.0f;
  float vx0 = (ix0f >= 0.0f && ix0f <= W1) ? 1.0f : 0.0f;
  float vx1 = (ix1f >= 0.0f && ix1f <= W1) ? 1.0f : 0.0f;
  float vy0 = (iy0f >= 0.0f && iy0f <= W1) ? 1.0f : 0.0f;
  float vy1 = (iy1f >= 0.0f && iy1f <= W1) ? 1.0f : 0.0f;
  int x0 = min(max((int)ix0f, 0), W - 1);
  int x1 = min(max((int)ix1f, 0), W - 1);
  int y0 = min(max((int)iy0f, 0), W - 1);
  int y1 = min(max((int)iy1f, 0), W - 1);
  float w00 = wy0 * wx0 * vy0 * vx0;
  float w01 = wy0 * wx1 * vy0 * vx1;
  float w10 = wy1 * wx0 * vy1 * vx0;
  float w11 = wy1 * wx1 * vy1 * vx1;
  size_t HW = (size_t)W * W;
  const float* b00 = t + (size_t)y0 * W + x0;
  const float* b01 = t + (size_t)y0 * W + x1;
  const float* b10 = t + (size_t)y1 * W + x0;
  const float* b11 = t + (size_t)y1 * W + x1;
#pragma unroll
  for (int c = 0; c < CH; ++c) {
    float v00 = b00[c * HW], v01 = b01[c * HW], v10 = b10[c * HW], v11 = b11[c * HW];
    acc[c] = fmaf(v00, w00, fmaf(v01, w01, fmaf(v10, w10, fmaf(v11, w11, acc[c]))));
  }
}

__global__ __launch_bounds__(256) void gather_chw_kernel(
    const float* __restrict__ x, const float* __restrict__ msk,
    const float* __restrict__ l1, const float* __restrict__ l2,
    const float* __restrict__ l3, const float* __restrict__ l4,
    float* __restrict__ out) {
  int p = blockIdx.x * blockDim.x + threadIdx.x;
  int wo = p & 511, ho = (p >> 9) & 511, b = p >> 18;
  float2 g = ((const float2*)x)[p];
  float gx = g.x * 2.0f - 1.0f;
  float gy = g.y * 2.0f - 1.0f;
  float m = msk[p];
  float acc[CH];
#pragma unroll
  for (int c = 0; c < CH; ++c) acc[c] = 0.0f;
  sample_chw(l1, 1024, gx, gy, acc);
  sample_chw(l2, 512, gx, gy, acc);
  sample_chw(l3, 256, gx, gy, acc);
  sample_chw(l4, 128, gx, gy, acc);
  size_t obase = (size_t)b * (CH * 262144) + (size_t)ho * 512 + wo;
#pragma unroll
  for (int c = 0; c < CH; ++c) out[obase + (size_t)c * 262144] = acc[c] * m;
}

extern "C" void kernel_launch(void* const* d_in, const int* in_sizes, int n_in,
                              void* d_out, int out_size, void* d_ws, size_t ws_size,
                              hipStream_t stream) {
  const float* x   = (const float*)d_in[0];
  const float* msk = (const float*)d_in[1];
  const float* l1  = (const float*)d_in[2];
  const float* l2  = (const float*)d_in[3];
  const float* l3  = (const float*)d_in[4];
  const float* l4  = (const float*)d_in[5];
  float* out = (float*)d_out;

  const size_t n_texel = 1048576 + 262144 + 65536 + 16384;      // 1392640
  const size_t tex_bytes = n_texel * CH * sizeof(__half);        // ~44.6 MB
  const size_t ws2_bytes = (size_t)NPIX * CH * sizeof(__half);   // 32 MB
  const size_t rec_bytes = (size_t)NPIX * sizeof(float4);        // 16 MB
  const size_t need_bin  = ws2_bytes + tex_bytes + rec_bytes;
  const size_t need_f16  = tex_bytes;

  if (ws_size >= need_bin) {
    char* base = (char*)d_ws;
    __half* ws2    = (__half*)base;
    __half* w1     = (__half*)(base + ws2_bytes);
    __half* w2     = w1 + (size_t)1048576 * CH;
    __half* w3     = w2 + (size_t)262144 * CH;
    __half* w4     = w3 + (size_t)65536 * CH;
    float4* pixrec = (float4*)(base + ws2_bytes + tex_bytes);
    // Sort metadata aliases into ws2 (dead once gather starts writing ws2):
    unsigned* hist    = (unsigned*)base;                          // 4 MB
    unsigned* partial = hist + (size_t)NBLK_SORT * NBINS;         // 256 KB
    unsigned* totals  = partial + (size_t)SEGS * NBINS;           // 16 KB
    unsigned* binbase = totals + NBINS;                           // 16 KB

    interleave_all_kernel<<<(int)(n_texel / 256), 256, 0, stream>>>(
        l1, l2, l3, l4, w1, w2, w3, w4);
    hist_kernel<<<NBLK_SORT, 256, 0, stream>>>((const float2*)x, hist);
    segsum_kernel<<<SEGS * NBINS / 256, 256, 0, stream>>>(hist, partial);
    segscan_kernel<<<NBINS / 256, 256, 0, stream>>>(partial, totals);
    scan_kernel<<<1, 1024, 0, stream>>>(totals, binbase);
    colscan_kernel<<<SEGS * NBINS / 256, 256, 0, stream>>>(hist, partial, binbase);
    scatter2_kernel<<<NBLK_SORT, 256, 0, stream>>>((const float2*)x, msk, hist, pixrec);
    gather_binned_kernel<<<NPIX / 256, 256, 0, stream>>>(pixrec, w1, w2, w3, w4, ws2);
    unscatter16_kernel<<<NPIX / 4 / 256, 256, 0, stream>>>(ws2, out);
  } else if (ws_size >= need_f16) {
    __half* w1 = (__half*)d_ws;
    __half* w2 = w1 + (size_t)1048576 * CH;
    __half* w3 = w2 + (size_t)262144 * CH;
    __half* w4 = w3 + (size_t)65536 * CH;
    interleave_all_kernel<<<(int)(n_texel / 256), 256, 0, stream>>>(
        l1, l2, l3, l4, w1, w2, w3, w4);
    gather_hwc16_kernel<<<NPIX / 256, 256, 0, stream>>>(x, msk, w1, w2, w3, w4, out);
  } else {
    gather_chw_kernel<<<NPIX / 256, 256, 0, stream>>>(x, msk, l1, l2, l3, l4, out);
  }
}

// Round 7
// 122.974 us; speedup vs baseline: 2.2098x; 1.0150x over previous
//
#include <hip/hip_runtime.h>
#include <hip/hip_fp16.h>

#define CH 16
#define NPIX (4 * 512 * 512)
#define NBINS 4096        // 64x64 bins of 16x16 layer1 texels
#define NBLK_SORT 256     // sort-pass blocks
#define PPB (NPIX / NBLK_SORT)   // 4096 pixels per sort block
#define SEGS 16           // k-segments for the hist column scan

// ---------------------------------------------------------------------------
// Fused repack: all 4 pyramid layers [C,H,W] f32 -> [H,W,C] fp16 interleaved.
// ---------------------------------------------------------------------------
__global__ __launch_bounds__(256) void interleave_all_kernel(
    const float* __restrict__ l1, const float* __restrict__ l2,
    const float* __restrict__ l3, const float* __restrict__ l4,
    __half* __restrict__ w1, __half* __restrict__ w2,
    __half* __restrict__ w3, __half* __restrict__ w4) {
  int g = blockIdx.x * blockDim.x + threadIdx.x;
  const float* src; __half* dst; int HW, p;
  if (g < 1048576)      { src = l1; dst = w1; HW = 1048576; p = g; }
  else if (g < 1310720) { src = l2; dst = w2; HW = 262144;  p = g - 1048576; }
  else if (g < 1376256) { src = l3; dst = w3; HW = 65536;   p = g - 1310720; }
  else                  { src = l4; dst = w4; HW = 16384;   p = g - 1376256; }
  union { __half h[CH]; uint4 u[2]; } pk;
#pragma unroll
  for (int c = 0; c < CH; ++c) pk.h[c] = __float2half(src[(size_t)c * HW + p]);
  uint4* d = (uint4*)(dst + (size_t)p * CH);
  d[0] = pk.u[0];
  d[1] = pk.u[1];
}

// ---------------------------------------------------------------------------
// Half-texel corner: load 8 fp16 channels (1x uint4), FMA into f32 acc[8].
// ---------------------------------------------------------------------------
__device__ __forceinline__ void corner_fma_h(const __half* __restrict__ t,
                                             size_t texel, int h, float w,
                                             float acc[8]) {
  union { uint4 u; __half2 hh[4]; } a;
  a.u = ((const uint4*)t)[texel * 2 + h];
#pragma unroll
  for (int i = 0; i < 4; ++i) {
    float2 f = __half22float2(a.hh[i]);
    acc[2 * i + 0] = fmaf(f.x, w, acc[2 * i + 0]);
    acc[2 * i + 1] = fmaf(f.y, w, acc[2 * i + 1]);
  }
}

// Bilinear sample of 8 channels (half h) of one fp16 [H,W,C] layer.
__device__ __forceinline__ void sample_hwc16h(const __half* __restrict__ t, int W,
                                              float gx, float gy, int h,
                                              float acc[8]) {
  const float W1 = (float)(W - 1);
  float ix = (gx + 1.0f) * 0.5f * W1;
  float iy = (gy + 1.0f) * 0.5f * W1;
  float ix0f = floorf(ix), iy0f = floorf(iy);
  float wx1 = ix - ix0f, wy1 = iy - iy0f;
  float wx0 = 1.0f - wx1, wy0 = 1.0f - wy1;
  float ix1f = ix0f + 1.0f, iy1f = iy0f + 1.0f;
  float vx0 = (ix0f >= 0.0f && ix0f <= W1) ? 1.0f : 0.0f;
  float vx1 = (ix1f >= 0.0f && ix1f <= W1) ? 1.0f : 0.0f;
  float vy0 = (iy0f >= 0.0f && iy0f <= W1) ? 1.0f : 0.0f;
  float vy1 = (iy1f >= 0.0f && iy1f <= W1) ? 1.0f : 0.0f;
  int x0 = min(max((int)ix0f, 0), W - 1);
  int x1 = min(max((int)ix1f, 0), W - 1);
  int y0 = min(max((int)iy0f, 0), W - 1);
  int y1 = min(max((int)iy1f, 0), W - 1);
  float w00 = wy0 * wx0 * vy0 * vx0;
  float w01 = wy0 * wx1 * vy0 * vx1;
  float w10 = wy1 * wx0 * vy1 * vx0;
  float w11 = wy1 * wx1 * vy1 * vx1;
  corner_fma_h(t, (size_t)y0 * W + x0, h, w00, acc);
  corner_fma_h(t, (size_t)y0 * W + x1, h, w01, acc);
  corner_fma_h(t, (size_t)y1 * W + x0, h, w10, acc);
  corner_fma_h(t, (size_t)y1 * W + x1, h, w11, acc);
}

// Full-texel version (for output-order fallback).
__device__ __forceinline__ void corner_fma(const __half* __restrict__ t,
                                           size_t texel, float w, float acc[CH]) {
  const uint4* q = (const uint4*)(t + texel * CH);
  union { uint4 u; __half2 h[4]; } a, b;
  a.u = q[0];
  b.u = q[1];
#pragma unroll
  for (int i = 0; i < 4; ++i) {
    float2 f = __half22float2(a.h[i]);
    acc[2 * i + 0] = fmaf(f.x, w, acc[2 * i + 0]);
    acc[2 * i + 1] = fmaf(f.y, w, acc[2 * i + 1]);
  }
#pragma unroll
  for (int i = 0; i < 4; ++i) {
    float2 f = __half22float2(b.h[i]);
    acc[8 + 2 * i + 0] = fmaf(f.x, w, acc[8 + 2 * i + 0]);
    acc[8 + 2 * i + 1] = fmaf(f.y, w, acc[8 + 2 * i + 1]);
  }
}

__device__ __forceinline__ void sample_hwc16(const __half* __restrict__ t, int W,
                                             float gx, float gy, float acc[CH]) {
  const float W1 = (float)(W - 1);
  float ix = (gx + 1.0f) * 0.5f * W1;
  float iy = (gy + 1.0f) * 0.5f * W1;
  float ix0f = floorf(ix), iy0f = floorf(iy);
  float wx1 = ix - ix0f, wy1 = iy - iy0f;
  float wx0 = 1.0f - wx1, wy0 = 1.0f - wy1;
  float ix1f = ix0f + 1.0f, iy1f = iy0f + 1.0f;
  float vx0 = (ix0f >= 0.0f && ix0f <= W1) ? 1.0f : 0.0f;
  float vx1 = (ix1f >= 0.0f && ix1f <= W1) ? 1.0f : 0.0f;
  float vy0 = (iy0f >= 0.0f && iy0f <= W1) ? 1.0f : 0.0f;
  float vy1 = (iy1f >= 0.0f && iy1f <= W1) ? 1.0f : 0.0f;
  int x0 = min(max((int)ix0f, 0), W - 1);
  int x1 = min(max((int)ix1f, 0), W - 1);
  int y0 = min(max((int)iy0f, 0), W - 1);
  int y1 = min(max((int)iy1f, 0), W - 1);
  float w00 = wy0 * wx0 * vy0 * vx0;
  float w01 = wy0 * wx1 * vy0 * vx1;
  float w10 = wy1 * wx0 * vy1 * vx0;
  float w11 = wy1 * wx1 * vy1 * vx1;
  corner_fma(t, (size_t)y0 * W + x0, w00, acc);
  corner_fma(t, (size_t)y0 * W + x1, w01, acc);
  corner_fma(t, (size_t)y1 * W + x0, w10, acc);
  corner_fma(t, (size_t)y1 * W + x1, w11, acc);
}

// ---------------------------------------------------------------------------
// Binning: bin = 16x16-texel tile at layer1 (1024^2) resolution.
// ---------------------------------------------------------------------------
__device__ __forceinline__ int bin_of(float xv, float yv) {
  int bx = min(max((int)(xv * 1023.0f), 0), 1023) >> 4;
  int by = min(max((int)(yv * 1023.0f), 0), 1023) >> 4;
  return (by << 6) + bx;
}

// Pass A: per-sort-block LDS histogram -> hist[blk][NBINS]. No global atomics.
__global__ __launch_bounds__(256) void hist_kernel(
    const float2* __restrict__ x, unsigned* __restrict__ hist) {
  __shared__ unsigned h[NBINS];
  int tid = threadIdx.x, blk = blockIdx.x;
#pragma unroll
  for (int i = 0; i < NBINS / 256; ++i) h[i * 256 + tid] = 0;
  __syncthreads();
  int base = blk * PPB;
#pragma unroll 4
  for (int c = 0; c < PPB / 256; ++c) {
    float2 g = x[base + c * 256 + tid];
    atomicAdd(&h[bin_of(g.x, g.y)], 1u);
  }
  __syncthreads();
#pragma unroll
  for (int i = 0; i < NBINS / 256; ++i)
    hist[(size_t)blk * NBINS + i * 256 + tid] = h[i * 256 + tid];
}

// Pass B1: per-segment column sums.
__global__ __launch_bounds__(256) void segsum_kernel(
    const unsigned* __restrict__ hist, unsigned* __restrict__ partial) {
  int gid = blockIdx.x * 256 + threadIdx.x;  // SEGS*NBINS
  int s = gid >> 12, bin = gid & (NBINS - 1);
  unsigned sum = 0;
#pragma unroll
  for (int k = 0; k < NBLK_SORT / SEGS; ++k)
    sum += hist[(size_t)(s * (NBLK_SORT / SEGS) + k) * NBINS + bin];
  partial[gid] = sum;
}

// Pass B2: per-bin exclusive scan over segments; totals[bin] = column total.
__global__ __launch_bounds__(256) void segscan_kernel(
    unsigned* __restrict__ partial, unsigned* __restrict__ totals) {
  int bin = blockIdx.x * 256 + threadIdx.x;
  unsigned run = 0;
#pragma unroll
  for (int s = 0; s < SEGS; ++s) {
    unsigned v = partial[s * NBINS + bin];
    partial[s * NBINS + bin] = run;
    run += v;
  }
  totals[bin] = run;
}

// Pass B3: exclusive scan of 4096 totals -> binbase (one block, 1024 threads).
__global__ __launch_bounds__(1024) void scan_kernel(
    const unsigned* __restrict__ counts, unsigned* __restrict__ cursor) {
  __shared__ unsigned part[1024];
  int t = threadIdx.x;
  unsigned c0 = counts[4 * t + 0], c1 = counts[4 * t + 1];
  unsigned c2 = counts[4 * t + 2], c3 = counts[4 * t + 3];
  part[t] = c0 + c1 + c2 + c3;
  __syncthreads();
  for (int off = 1; off < 1024; off <<= 1) {
    unsigned v = (t >= off) ? part[t - off] : 0u;
    __syncthreads();
    part[t] += v;
    __syncthreads();
  }
  unsigned base = (t > 0) ? part[t - 1] : 0u;  // exclusive
  cursor[4 * t + 0] = base;
  cursor[4 * t + 1] = base + c0;
  cursor[4 * t + 2] = base + c0 + c1;
  cursor[4 * t + 3] = base + c0 + c1 + c2;
}

// Pass B4: convert hist[k][bin] counts -> global exclusive base for (k, bin).
__global__ __launch_bounds__(256) void colscan_kernel(
    unsigned* __restrict__ hist, const unsigned* __restrict__ partial,
    const unsigned* __restrict__ binbase) {
  int gid = blockIdx.x * 256 + threadIdx.x;
  int s = gid >> 12, bin = gid & (NBINS - 1);
  unsigned run = partial[s * NBINS + bin] + binbase[bin];
#pragma unroll
  for (int k = 0; k < NBLK_SORT / SEGS; ++k) {
    size_t idx = (size_t)(s * (NBLK_SORT / SEGS) + k) * NBINS + bin;
    unsigned v = hist[idx];
    hist[idx] = run;
    run += v;
  }
}

// Pass C: scatter with LDS cursors seeded from hist bases. No global atomics.
__global__ __launch_bounds__(256) void scatter2_kernel(
    const float2* __restrict__ x, const float* __restrict__ msk,
    const unsigned* __restrict__ hist, float4* __restrict__ pixrec) {
  __shared__ unsigned cur[NBINS];
  int tid = threadIdx.x, blk = blockIdx.x;
#pragma unroll
  for (int i = 0; i < NBINS / 256; ++i)
    cur[i * 256 + tid] = hist[(size_t)blk * NBINS + i * 256 + tid];
  __syncthreads();
  int base = blk * PPB;
#pragma unroll 4
  for (int c = 0; c < PPB / 256; ++c) {
    int p = base + c * 256 + tid;
    float2 g = x[p];
    float m = msk[p];
    unsigned i = atomicAdd(&cur[bin_of(g.x, g.y)], 1u);
    pixrec[i] = make_float4(g.x, g.y, __uint_as_float((unsigned)p), m);
  }
}

// Gather in bin order, 2 threads per pixel (8 channels each). No in-block
// sort: per-thread load chain is halved and wave count doubled for TLP.
__global__ __launch_bounds__(256) void gather_binned2_kernel(
    const float4* __restrict__ pixrec,
    const __half* __restrict__ t1, const __half* __restrict__ t2,
    const __half* __restrict__ t3, const __half* __restrict__ t4,
    __half* __restrict__ ws2) {
  // 8192 blocks; XCD-chunked swizzle -> 1024-block contiguous chunks.
  int bid = blockIdx.x;
  int swz = (bid & 7) * 1024 + (bid >> 3);
  int g = swz * 256 + threadIdx.x;
  int i = g >> 1;        // pixel slot in bin order
  int h = g & 1;         // channel half (0: ch0-7, 1: ch8-15)
  float4 r = pixrec[i];
  float gx = r.x * 2.0f - 1.0f;
  float gy = r.y * 2.0f - 1.0f;
  unsigned p = __float_as_uint(r.z);
  float m = r.w;
  float acc[8];
#pragma unroll
  for (int c = 0; c < 8; ++c) acc[c] = 0.0f;
  sample_hwc16h(t1, 1024, gx, gy, h, acc);
  sample_hwc16h(t2, 512, gx, gy, h, acc);
  sample_hwc16h(t3, 256, gx, gy, h, acc);
  sample_hwc16h(t4, 128, gx, gy, h, acc);
  union { __half2 hh[4]; uint4 u; } o;
#pragma unroll
  for (int c = 0; c < 4; ++c)
    o.hh[c] = __floats2half2_rn(acc[2 * c] * m, acc[2 * c + 1] * m);
  ((uint4*)(ws2 + (size_t)p * CH))[h] = o.u;
}

// Unscatter fp16 ws2[p][16] -> f32 out[B][C][Ho][Wo]. 4 pixels per thread.
__global__ __launch_bounds__(256) void unscatter16_kernel(
    const __half* __restrict__ ws2, float* __restrict__ out) {
  int t = blockIdx.x * blockDim.x + threadIdx.x;  // [0, NPIX/4)
  int p0 = t * 4;
  int wo = p0 & 511, ho = (p0 >> 9) & 511, b = p0 >> 18;
  const uint4* s = (const uint4*)ws2;
  union { uint4 u[2]; __half2 h[8]; } v[4];
#pragma unroll
  for (int j = 0; j < 4; ++j) {
    v[j].u[0] = s[(size_t)(p0 + j) * 2 + 0];
    v[j].u[1] = s[(size_t)(p0 + j) * 2 + 1];
  }
  size_t obase = (size_t)b * (CH * 262144) + (size_t)ho * 512 + wo;
#pragma unroll
  for (int ch = 0; ch < CH; ++ch) {
    float4 o;
    o.x = __half2float(((ch & 1) ? __high2half(v[0].h[ch >> 1]) : __low2half(v[0].h[ch >> 1])));
    o.y = __half2float(((ch & 1) ? __high2half(v[1].h[ch >> 1]) : __low2half(v[1].h[ch >> 1])));
    o.z = __half2float(((ch & 1) ? __high2half(v[2].h[ch >> 1]) : __low2half(v[2].h[ch >> 1])));
    o.w = __half2float(((ch & 1) ? __high2half(v[3].h[ch >> 1]) : __low2half(v[3].h[ch >> 1])));
    *(float4*)(out + obase + (size_t)ch * 262144) = o;
  }
}

// ---------------------------------------------------------------------------
// Fallback 1: direct output-order gather from fp16 interleaved (R1 kernel).
// ---------------------------------------------------------------------------
__global__ __launch_bounds__(256) void gather_hwc16_kernel(
    const float* __restrict__ x, const float* __restrict__ msk,
    const __half* __restrict__ t1, const __half* __restrict__ t2,
    const __half* __restrict__ t3, const __half* __restrict__ t4,
    float* __restrict__ out) {
  int p = blockIdx.x * blockDim.x + threadIdx.x;
  int wo = p & 511, ho = (p >> 9) & 511, b = p >> 18;
  float2 g = ((const float2*)x)[p];
  float gx = g.x * 2.0f - 1.0f;
  float gy = g.y * 2.0f - 1.0f;
  float m = msk[p];
  float acc[CH];
#pragma unroll
  for (int c = 0; c < CH; ++c) acc[c] = 0.0f;
  sample_hwc16(t1, 1024, gx, gy, acc);
  sample_hwc16(t2, 512, gx, gy, acc);
  sample_hwc16(t3, 256, gx, gy, acc);
  sample_hwc16(t4, 128, gx, gy, acc);
  size_t obase = (size_t)b * (CH * 262144) + (size_t)ho * 512 + wo;
#pragma unroll
  for (int c = 0; c < CH; ++c) out[obase + (size_t)c * 262144] = acc[c] * m;
}

// ---------------------------------------------------------------------------
// Fallback 2: direct gather from native [C, H, W] f32 layout.
// ---------------------------------------------------------------------------
__device__ __forceinline__ void sample_chw(const float* __restrict__ t, int W,
                                           float gx, float gy, float acc[CH]) {
  const float W1 = (float)(W - 1);
  float ix = (gx + 1.0f) * 0.5f * W1;
  float iy = (gy + 1.0f) * 0.5f * W1;
  float ix0f = floorf(ix), iy0f = floorf(iy);
  float wx1 = ix - ix0f, wy1 = iy - iy0f;
  float wx0 = 1.0f - wx1, wy0 = 1.0f - wy1;
  float ix1f = ix0f + 1.0f, iy1f = iy0f + 1.0f;
  float vx0 = (ix0f >= 0.0f && ix0f <= W1) ? 1.0f : 0.0f;
  float vx1 = (ix1f >= 0.0f && ix1f <= W1) ? 1.0f : 0.0f;
  float vy0 = (iy0f >= 0.0f && iy0f <= W1) ? 1.0f : 0.0f;
  float vy1 = (iy1f >= 0.0f && iy1f <= W1) ? 1.0f : 0.0f;
  int x0 = min(max((int)ix0f, 0), W - 1);
  int x1 = min(max((int)ix1f, 0), W - 1);
  int y0 = min(max((int)iy0f, 0), W - 1);
  int y1 = min(max((int)iy1f, 0), W - 1);
  float w00 = wy0 * wx0 * vy0 * vx0;
  float w01 = wy0 * wx1 * vy0 * vx1;
  float w10 = wy1 * wx0 * vy1 * vx0;
  float w11 = wy1 * wx1 * vy1 * vx1;
  size_t HW = (size_t)W * W;
  const float* b00 = t + (size_t)y0 * W + x0;
  const float* b01 = t + (size_t)y0 * W + x1;
  const float* b10 = t + (size_t)y1 * W + x0;
  const float* b11 = t + (size_t)y1 * W + x1;
#pragma unroll
  for (int c = 0; c < CH; ++c) {
    float v00 = b00[c * HW], v01 = b01[c * HW], v10 = b10[c * HW], v11 = b11[c * HW];
    acc[c] = fmaf(v00, w00, fmaf(v01, w01, fmaf(v10, w10, fmaf(v11, w11, acc[c]))));
  }
}

__global__ __launch_bounds__(256) void gather_chw_kernel(
    const float* __restrict__ x, const float* __restrict__ msk,
    const float* __restrict__ l1, const float* __restrict__ l2,
    const float* __restrict__ l3, const float* __restrict__ l4,
    float* __restrict__ out) {
  int p = blockIdx.x * blockDim.x + threadIdx.x;
  int wo = p & 511, ho = (p >> 9) & 511, b = p >> 18;
  float2 g = ((const float2*)x)[p];
  float gx = g.x * 2.0f - 1.0f;
  float gy = g.y * 2.0f - 1.0f;
  float m = msk[p];
  float acc[CH];
#pragma unroll
  for (int c = 0; c < CH; ++c) acc[c] = 0.0f;
  sample_chw(l1, 1024, gx, gy, acc);
  sample_chw(l2, 512, gx, gy, acc);
  sample_chw(l3, 256, gx, gy, acc);
  sample_chw(l4, 128, gx, gy, acc);
  size_t obase = (size_t)b * (CH * 262144) + (size_t)ho * 512 + wo;
#pragma unroll
  for (int c = 0; c < CH; ++c) out[obase + (size_t)c * 262144] = acc[c] * m;
}

extern "C" void kernel_launch(void* const* d_in, const int* in_sizes, int n_in,
                              void* d_out, int out_size, void* d_ws, size_t ws_size,
                              hipStream_t stream) {
  const float* x   = (const float*)d_in[0];
  const float* msk = (const float*)d_in[1];
  const float* l1  = (const float*)d_in[2];
  const float* l2  = (const float*)d_in[3];
  const float* l3  = (const float*)d_in[4];
  const float* l4  = (const float*)d_in[5];
  float* out = (float*)d_out;

  const size_t n_texel = 1048576 + 262144 + 65536 + 16384;      // 1392640
  const size_t tex_bytes = n_texel * CH * sizeof(__half);        // ~44.6 MB
  const size_t ws2_bytes = (size_t)NPIX * CH * sizeof(__half);   // 32 MB
  const size_t rec_bytes = (size_t)NPIX * sizeof(float4);        // 16 MB
  const size_t need_bin  = ws2_bytes + tex_bytes + rec_bytes;
  const size_t need_f16  = tex_bytes;

  if (ws_size >= need_bin) {
    char* base = (char*)d_ws;
    __half* ws2    = (__half*)base;
    __half* w1     = (__half*)(base + ws2_bytes);
    __half* w2     = w1 + (size_t)1048576 * CH;
    __half* w3     = w2 + (size_t)262144 * CH;
    __half* w4     = w3 + (size_t)65536 * CH;
    float4* pixrec = (float4*)(base + ws2_bytes + tex_bytes);
    // Sort metadata aliases into ws2 (dead once gather starts writing ws2):
    unsigned* hist    = (unsigned*)base;                          // 4 MB
    unsigned* partial = hist + (size_t)NBLK_SORT * NBINS;         // 256 KB
    unsigned* totals  = partial + (size_t)SEGS * NBINS;           // 16 KB
    unsigned* binbase = totals + NBINS;                           // 16 KB

    interleave_all_kernel<<<(int)(n_texel / 256), 256, 0, stream>>>(
        l1, l2, l3, l4, w1, w2, w3, w4);
    hist_kernel<<<NBLK_SORT, 256, 0, stream>>>((const float2*)x, hist);
    segsum_kernel<<<SEGS * NBINS / 256, 256, 0, stream>>>(hist, partial);
    segscan_kernel<<<NBINS / 256, 256, 0, stream>>>(partial, totals);
    scan_kernel<<<1, 1024, 0, stream>>>(totals, binbase);
    colscan_kernel<<<SEGS * NBINS / 256, 256, 0, stream>>>(hist, partial, binbase);
    scatter2_kernel<<<NBLK_SORT, 256, 0, stream>>>((const float2*)x, msk, hist, pixrec);
    gather_binned2_kernel<<<NPIX * 2 / 256, 256, 0, stream>>>(pixrec, w1, w2, w3, w4, ws2);
    unscatter16_kernel<<<NPIX / 4 / 256, 256, 0, stream>>>(ws2, out);
  } else if (ws_size >= need_f16) {
    __half* w1 = (__half*)d_ws;
    __half* w2 = w1 + (size_t)1048576 * CH;
    __half* w3 = w2 + (size_t)262144 * CH;
    __half* w4 = w3 + (size_t)65536 * CH;
    interleave_all_kernel<<<(int)(n_texel / 256), 256, 0, stream>>>(
        l1, l2, l3, l4, w1, w2, w3, w4);
    gather_hwc16_kernel<<<NPIX / 256, 256, 0, stream>>>(x, msk, w1, w2, w3, w4, out);
  } else {
    gather_chw_kernel<<<NPIX / 256, 256, 0, stream>>>(x, msk, l1, l2, l3, l4, out);
  }
}

// Round 8
// 112.323 us; speedup vs baseline: 2.4193x; 1.0948x over previous
//
#include <hip/hip_runtime.h>
#include <hip/hip_fp16.h>

#define CH 16
#define NPIX (4 * 512 * 512)
#define NBINS 4096        // 64x64 bins of 16x16 layer1 texels
#define NBLK_SORT 256     // sort-pass blocks
#define PPB (NPIX / NBLK_SORT)   // 4096 pixels per sort block
#define SEGS 16           // k-segments for the hist column scan

// ---------------------------------------------------------------------------
// Fused repack: all 4 pyramid layers [C,H,W] f32 -> [H,W,C] fp16 interleaved.
// ---------------------------------------------------------------------------
__global__ __launch_bounds__(256) void interleave_all_kernel(
    const float* __restrict__ l1, const float* __restrict__ l2,
    const float* __restrict__ l3, const float* __restrict__ l4,
    __half* __restrict__ w1, __half* __restrict__ w2,
    __half* __restrict__ w3, __half* __restrict__ w4) {
  int g = blockIdx.x * blockDim.x + threadIdx.x;
  const float* src; __half* dst; int HW, p;
  if (g < 1048576)      { src = l1; dst = w1; HW = 1048576; p = g; }
  else if (g < 1310720) { src = l2; dst = w2; HW = 262144;  p = g - 1048576; }
  else if (g < 1376256) { src = l3; dst = w3; HW = 65536;   p = g - 1310720; }
  else                  { src = l4; dst = w4; HW = 16384;   p = g - 1376256; }
  union { __half h[CH]; uint4 u[2]; } pk;
#pragma unroll
  for (int c = 0; c < CH; ++c) pk.h[c] = __float2half(src[(size_t)c * HW + p]);
  uint4* d = (uint4*)(dst + (size_t)p * CH);
  d[0] = pk.u[0];
  d[1] = pk.u[1];
}

// ---------------------------------------------------------------------------
// Packed-fp16 bilinear sample of 8 channels (half h) of one fp16 [H,W,C]
// layer. All 4 corner loads issued up-front (ILP); per-layer blend in fp16
// (convex combination -> ~2 ulp error), layer result added to f32 acc.
// ---------------------------------------------------------------------------
__device__ __forceinline__ void sample_hwc16h_pk(const __half* __restrict__ t,
                                                 int W, float gx, float gy,
                                                 int h, float acc[8]) {
  const float W1 = (float)(W - 1);
  float ix = (gx + 1.0f) * 0.5f * W1;
  float iy = (gy + 1.0f) * 0.5f * W1;
  float ix0f = floorf(ix), iy0f = floorf(iy);
  float wx1 = ix - ix0f, wy1 = iy - iy0f;
  float wx0 = 1.0f - wx1, wy0 = 1.0f - wy1;
  float ix1f = ix0f + 1.0f, iy1f = iy0f + 1.0f;
  float vx0 = (ix0f >= 0.0f && ix0f <= W1) ? 1.0f : 0.0f;
  float vx1 = (ix1f >= 0.0f && ix1f <= W1) ? 1.0f : 0.0f;
  float vy0 = (iy0f >= 0.0f && iy0f <= W1) ? 1.0f : 0.0f;
  float vy1 = (iy1f >= 0.0f && iy1f <= W1) ? 1.0f : 0.0f;
  int x0 = min(max((int)ix0f, 0), W - 1);
  int x1 = min(max((int)ix1f, 0), W - 1);
  int y0 = min(max((int)iy0f, 0), W - 1);
  int y1 = min(max((int)iy1f, 0), W - 1);
  const uint4* base = (const uint4*)t;
  union { uint4 u; __half2 hh[4]; } a00, a01, a10, a11;
  a00.u = base[((size_t)y0 * W + x0) * 2 + h];
  a01.u = base[((size_t)y0 * W + x1) * 2 + h];
  a10.u = base[((size_t)y1 * W + x0) * 2 + h];
  a11.u = base[((size_t)y1 * W + x1) * 2 + h];
  __half2 w00h = __float2half2_rn(wy0 * wx0 * vy0 * vx0);
  __half2 w01h = __float2half2_rn(wy0 * wx1 * vy0 * vx1);
  __half2 w10h = __float2half2_rn(wy1 * wx0 * vy1 * vx0);
  __half2 w11h = __float2half2_rn(wy1 * wx1 * vy1 * vx1);
#pragma unroll
  for (int i = 0; i < 4; ++i) {
    __half2 s = __hmul2(a00.hh[i], w00h);
    s = __hfma2(a01.hh[i], w01h, s);
    s = __hfma2(a10.hh[i], w10h, s);
    s = __hfma2(a11.hh[i], w11h, s);
    float2 f = __half22float2(s);
    acc[2 * i + 0] += f.x;
    acc[2 * i + 1] += f.y;
  }
}

// Full-texel f32 version (for output-order fallback).
__device__ __forceinline__ void corner_fma(const __half* __restrict__ t,
                                           size_t texel, float w, float acc[CH]) {
  const uint4* q = (const uint4*)(t + texel * CH);
  union { uint4 u; __half2 h[4]; } a, b;
  a.u = q[0];
  b.u = q[1];
#pragma unroll
  for (int i = 0; i < 4; ++i) {
    float2 f = __half22float2(a.h[i]);
    acc[2 * i + 0] = fmaf(f.x, w, acc[2 * i + 0]);
    acc[2 * i + 1] = fmaf(f.y, w, acc[2 * i + 1]);
  }
#pragma unroll
  for (int i = 0; i < 4; ++i) {
    float2 f = __half22float2(b.h[i]);
    acc[8 + 2 * i + 0] = fmaf(f.x, w, acc[8 + 2 * i + 0]);
    acc[8 + 2 * i + 1] = fmaf(f.y, w, acc[8 + 2 * i + 1]);
  }
}

__device__ __forceinline__ void sample_hwc16(const __half* __restrict__ t, int W,
                                             float gx, float gy, float acc[CH]) {
  const float W1 = (float)(W - 1);
  float ix = (gx + 1.0f) * 0.5f * W1;
  float iy = (gy + 1.0f) * 0.5f * W1;
  float ix0f = floorf(ix), iy0f = floorf(iy);
  float wx1 = ix - ix0f, wy1 = iy - iy0f;
  float wx0 = 1.0f - wx1, wy0 = 1.0f - wy1;
  float ix1f = ix0f + 1.0f, iy1f = iy0f + 1.0f;
  float vx0 = (ix0f >= 0.0f && ix0f <= W1) ? 1.0f : 0.0f;
  float vx1 = (ix1f >= 0.0f && ix1f <= W1) ? 1.0f : 0.0f;
  float vy0 = (iy0f >= 0.0f && iy0f <= W1) ? 1.0f : 0.0f;
  float vy1 = (iy1f >= 0.0f && iy1f <= W1) ? 1.0f : 0.0f;
  int x0 = min(max((int)ix0f, 0), W - 1);
  int x1 = min(max((int)ix1f, 0), W - 1);
  int y0 = min(max((int)iy0f, 0), W - 1);
  int y1 = min(max((int)iy1f, 0), W - 1);
  float w00 = wy0 * wx0 * vy0 * vx0;
  float w01 = wy0 * wx1 * vy0 * vx1;
  float w10 = wy1 * wx0 * vy1 * vx0;
  float w11 = wy1 * wx1 * vy1 * vx1;
  corner_fma(t, (size_t)y0 * W + x0, w00, acc);
  corner_fma(t, (size_t)y0 * W + x1, w01, acc);
  corner_fma(t, (size_t)y1 * W + x0, w10, acc);
  corner_fma(t, (size_t)y1 * W + x1, w11, acc);
}

// ---------------------------------------------------------------------------
// Binning: bin = 16x16-texel tile at layer1 (1024^2) resolution.
// ---------------------------------------------------------------------------
__device__ __forceinline__ int bin_of(float xv, float yv) {
  int bx = min(max((int)(xv * 1023.0f), 0), 1023) >> 4;
  int by = min(max((int)(yv * 1023.0f), 0), 1023) >> 4;
  return (by << 6) + bx;
}

// Pass A: per-sort-block LDS histogram -> hist[blk][NBINS]. No global atomics.
__global__ __launch_bounds__(256) void hist_kernel(
    const float2* __restrict__ x, unsigned* __restrict__ hist) {
  __shared__ unsigned h[NBINS];
  int tid = threadIdx.x, blk = blockIdx.x;
#pragma unroll
  for (int i = 0; i < NBINS / 256; ++i) h[i * 256 + tid] = 0;
  __syncthreads();
  int base = blk * PPB;
#pragma unroll 4
  for (int c = 0; c < PPB / 256; ++c) {
    float2 g = x[base + c * 256 + tid];
    atomicAdd(&h[bin_of(g.x, g.y)], 1u);
  }
  __syncthreads();
#pragma unroll
  for (int i = 0; i < NBINS / 256; ++i)
    hist[(size_t)blk * NBINS + i * 256 + tid] = h[i * 256 + tid];
}

// Pass B1: per-segment column sums.
__global__ __launch_bounds__(256) void segsum_kernel(
    const unsigned* __restrict__ hist, unsigned* __restrict__ partial) {
  int gid = blockIdx.x * 256 + threadIdx.x;  // SEGS*NBINS
  int s = gid >> 12, bin = gid & (NBINS - 1);
  unsigned sum = 0;
#pragma unroll
  for (int k = 0; k < NBLK_SORT / SEGS; ++k)
    sum += hist[(size_t)(s * (NBLK_SORT / SEGS) + k) * NBINS + bin];
  partial[gid] = sum;
}

// Pass B2: per-bin exclusive scan over segments; totals[bin] = column total.
__global__ __launch_bounds__(256) void segscan_kernel(
    unsigned* __restrict__ partial, unsigned* __restrict__ totals) {
  int bin = blockIdx.x * 256 + threadIdx.x;
  unsigned run = 0;
#pragma unroll
  for (int s = 0; s < SEGS; ++s) {
    unsigned v = partial[s * NBINS + bin];
    partial[s * NBINS + bin] = run;
    run += v;
  }
  totals[bin] = run;
}

// Pass B3: exclusive scan of 4096 totals -> binbase (one block, 1024 threads).
__global__ __launch_bounds__(1024) void scan_kernel(
    const unsigned* __restrict__ counts, unsigned* __restrict__ cursor) {
  __shared__ unsigned part[1024];
  int t = threadIdx.x;
  unsigned c0 = counts[4 * t + 0], c1 = counts[4 * t + 1];
  unsigned c2 = counts[4 * t + 2], c3 = counts[4 * t + 3];
  part[t] = c0 + c1 + c2 + c3;
  __syncthreads();
  for (int off = 1; off < 1024; off <<= 1) {
    unsigned v = (t >= off) ? part[t - off] : 0u;
    __syncthreads();
    part[t] += v;
    __syncthreads();
  }
  unsigned base = (t > 0) ? part[t - 1] : 0u;  // exclusive
  cursor[4 * t + 0] = base;
  cursor[4 * t + 1] = base + c0;
  cursor[4 * t + 2] = base + c0 + c1;
  cursor[4 * t + 3] = base + c0 + c1 + c2;
}

// Pass B4: convert hist[k][bin] counts -> global exclusive base for (k, bin).
__global__ __launch_bounds__(256) void colscan_kernel(
    unsigned* __restrict__ hist, const unsigned* __restrict__ partial,
    const unsigned* __restrict__ binbase) {
  int gid = blockIdx.x * 256 + threadIdx.x;
  int s = gid >> 12, bin = gid & (NBINS - 1);
  unsigned run = partial[s * NBINS + bin] + binbase[bin];
#pragma unroll
  for (int k = 0; k < NBLK_SORT / SEGS; ++k) {
    size_t idx = (size_t)(s * (NBLK_SORT / SEGS) + k) * NBINS + bin;
    unsigned v = hist[idx];
    hist[idx] = run;
    run += v;
  }
}

// Pass C: scatter with LDS cursors seeded from hist bases. No global atomics.
__global__ __launch_bounds__(256) void scatter2_kernel(
    const float2* __restrict__ x, const float* __restrict__ msk,
    const unsigned* __restrict__ hist, float4* __restrict__ pixrec) {
  __shared__ unsigned cur[NBINS];
  int tid = threadIdx.x, blk = blockIdx.x;
#pragma unroll
  for (int i = 0; i < NBINS / 256; ++i)
    cur[i * 256 + tid] = hist[(size_t)blk * NBINS + i * 256 + tid];
  __syncthreads();
  int base = blk * PPB;
#pragma unroll 4
  for (int c = 0; c < PPB / 256; ++c) {
    int p = base + c * 256 + tid;
    float2 g = x[p];
    float m = msk[p];
    unsigned i = atomicAdd(&cur[bin_of(g.x, g.y)], 1u);
    pixrec[i] = make_float4(g.x, g.y, __uint_as_float((unsigned)p), m);
  }
}

// Gather in bin order, 2 threads per pixel (8 channels each), packed fp16
// corner blend with all-corners-up-front loads.
__global__ __launch_bounds__(256) void gather_binned2_kernel(
    const float4* __restrict__ pixrec,
    const __half* __restrict__ t1, const __half* __restrict__ t2,
    const __half* __restrict__ t3, const __half* __restrict__ t4,
    __half* __restrict__ ws2) {
  // 8192 blocks; XCD-chunked swizzle -> 1024-block contiguous chunks.
  int bid = blockIdx.x;
  int swz = (bid & 7) * 1024 + (bid >> 3);
  int g = swz * 256 + threadIdx.x;
  int i = g >> 1;        // pixel slot in bin order
  int h = g & 1;         // channel half (0: ch0-7, 1: ch8-15)
  float4 r = pixrec[i];
  float gx = r.x * 2.0f - 1.0f;
  float gy = r.y * 2.0f - 1.0f;
  unsigned p = __float_as_uint(r.z);
  float m = r.w;
  float acc[8];
#pragma unroll
  for (int c = 0; c < 8; ++c) acc[c] = 0.0f;
  sample_hwc16h_pk(t1, 1024, gx, gy, h, acc);
  sample_hwc16h_pk(t2, 512, gx, gy, h, acc);
  sample_hwc16h_pk(t3, 256, gx, gy, h, acc);
  sample_hwc16h_pk(t4, 128, gx, gy, h, acc);
  union { __half2 hh[4]; uint4 u; } o;
#pragma unroll
  for (int c = 0; c < 4; ++c)
    o.hh[c] = __floats2half2_rn(acc[2 * c] * m, acc[2 * c + 1] * m);
  ((uint4*)(ws2 + (size_t)p * CH))[h] = o.u;
}

// Unscatter fp16 ws2[p][16] -> f32 out[B][C][Ho][Wo]. 4 pixels per thread.
__global__ __launch_bounds__(256) void unscatter16_kernel(
    const __half* __restrict__ ws2, float* __restrict__ out) {
  int t = blockIdx.x * blockDim.x + threadIdx.x;  // [0, NPIX/4)
  int p0 = t * 4;
  int wo = p0 & 511, ho = (p0 >> 9) & 511, b = p0 >> 18;
  const uint4* s = (const uint4*)ws2;
  union { uint4 u[2]; __half2 h[8]; } v[4];
#pragma unroll
  for (int j = 0; j < 4; ++j) {
    v[j].u[0] = s[(size_t)(p0 + j) * 2 + 0];
    v[j].u[1] = s[(size_t)(p0 + j) * 2 + 1];
  }
  size_t obase = (size_t)b * (CH * 262144) + (size_t)ho * 512 + wo;
#pragma unroll
  for (int ch = 0; ch < CH; ++ch) {
    float4 o;
    o.x = __half2float(((ch & 1) ? __high2half(v[0].h[ch >> 1]) : __low2half(v[0].h[ch >> 1])));
    o.y = __half2float(((ch & 1) ? __high2half(v[1].h[ch >> 1]) : __low2half(v[1].h[ch >> 1])));
    o.z = __half2float(((ch & 1) ? __high2half(v[2].h[ch >> 1]) : __low2half(v[2].h[ch >> 1])));
    o.w = __half2float(((ch & 1) ? __high2half(v[3].h[ch >> 1]) : __low2half(v[3].h[ch >> 1])));
    *(float4*)(out + obase + (size_t)ch * 262144) = o;
  }
}

// ---------------------------------------------------------------------------
// Fallback 1: direct output-order gather from fp16 interleaved (R1 kernel).
// ---------------------------------------------------------------------------
__global__ __launch_bounds__(256) void gather_hwc16_kernel(
    const float* __restrict__ x, const float* __restrict__ msk,
    const __half* __restrict__ t1, const __half* __restrict__ t2,
    const __half* __restrict__ t3, const __half* __restrict__ t4,
    float* __restrict__ out) {
  int p = blockIdx.x * blockDim.x + threadIdx.x;
  int wo = p & 511, ho = (p >> 9) & 511, b = p >> 18;
  float2 g = ((const float2*)x)[p];
  float gx = g.x * 2.0f - 1.0f;
  float gy = g.y * 2.0f - 1.0f;
  float m = msk[p];
  float acc[CH];
#pragma unroll
  for (int c = 0; c < CH; ++c) acc[c] = 0.0f;
  sample_hwc16(t1, 1024, gx, gy, acc);
  sample_hwc16(t2, 512, gx, gy, acc);
  sample_hwc16(t3, 256, gx, gy, acc);
  sample_hwc16(t4, 128, gx, gy, acc);
  size_t obase = (size_t)b * (CH * 262144) + (size_t)ho * 512 + wo;
#pragma unroll
  for (int c = 0; c < CH; ++c) out[obase + (size_t)c * 262144] = acc[c] * m;
}

// ---------------------------------------------------------------------------
// Fallback 2: direct gather from native [C, H, W] f32 layout.
// ---------------------------------------------------------------------------
__device__ __forceinline__ void sample_chw(const float* __restrict__ t, int W,
                                           float gx, float gy, float acc[CH]) {
  const float W1 = (float)(W - 1);
  float ix = (gx + 1.0f) * 0.5f * W1;
  float iy = (gy + 1.0f) * 0.5f * W1;
  float ix0f = floorf(ix), iy0f = floorf(iy);
  float wx1 = ix - ix0f, wy1 = iy - iy0f;
  float wx0 = 1.0f - wx1, wy0 = 1.0f - wy1;
  float ix1f = ix0f + 1.0f, iy1f = iy0f + 1.0f;
  float vx0 = (ix0f >= 0.0f && ix0f <= W1) ? 1.0f : 0.0f;
  float vx1 = (ix1f >= 0.0f && ix1f <= W1) ? 1.0f : 0.0f;
  float vy0 = (iy0f >= 0.0f && iy0f <= W1) ? 1.0f : 0.0f;
  float vy1 = (iy1f >= 0.0f && iy1f <= W1) ? 1.0f : 0.0f;
  int x0 = min(max((int)ix0f, 0), W - 1);
  int x1 = min(max((int)ix1f, 0), W - 1);
  int y0 = min(max((int)iy0f, 0), W - 1);
  int y1 = min(max((int)iy1f, 0), W - 1);
  float w00 = wy0 * wx0 * vy0 * vx0;
  float w01 = wy0 * wx1 * vy0 * vx1;
  float w10 = wy1 * wx0 * vy1 * vx0;
  float w11 = wy1 * wx1 * vy1 * vx1;
  size_t HW = (size_t)W * W;
  const float* b00 = t + (size_t)y0 * W + x0;
  const float* b01 = t + (size_t)y0 * W + x1;
  const float* b10 = t + (size_t)y1 * W + x0;
  const float* b11 = t + (size_t)y1 * W + x1;
#pragma unroll
  for (int c = 0; c < CH; ++c) {
    float v00 = b00[c * HW], v01 = b01[c * HW], v10 = b10[c * HW], v11 = b11[c * HW];
    acc[c] = fmaf(v00, w00, fmaf(v01, w01, fmaf(v10, w10, fmaf(v11, w11, acc[c]))));
  }
}

__global__ __launch_bounds__(256) void gather_chw_kernel(
    const float* __restrict__ x, const float* __restrict__ msk,
    const float* __restrict__ l1, const float* __restrict__ l2,
    const float* __restrict__ l3, const float* __restrict__ l4,
    float* __restrict__ out) {
  int p = blockIdx.x * blockDim.x + threadIdx.x;
  int wo = p & 511, ho = (p >> 9) & 511, b = p >> 18;
  float2 g = ((const float2*)x)[p];
  float gx = g.x * 2.0f - 1.0f;
  float gy = g.y * 2.0f - 1.0f;
  float m = msk[p];
  float acc[CH];
#pragma unroll
  for (int c = 0; c < CH; ++c) acc[c] = 0.0f;
  sample_chw(l1, 1024, gx, gy, acc);
  sample_chw(l2, 512, gx, gy, acc);
  sample_chw(l3, 256, gx, gy, acc);
  sample_chw(l4, 128, gx, gy, acc);
  size_t obase = (size_t)b * (CH * 262144) + (size_t)ho * 512 + wo;
#pragma unroll
  for (int c = 0; c < CH; ++c) out[obase + (size_t)c * 262144] = acc[c] * m;
}

extern "C" void kernel_launch(void* const* d_in, const int* in_sizes, int n_in,
                              void* d_out, int out_size, void* d_ws, size_t ws_size,
                              hipStream_t stream) {
  const float* x   = (const float*)d_in[0];
  const float* msk = (const float*)d_in[1];
  const float* l1  = (const float*)d_in[2];
  const float* l2  = (const float*)d_in[3];
  const float* l3  = (const float*)d_in[4];
  const float* l4  = (const float*)d_in[5];
  float* out = (float*)d_out;

  const size_t n_texel = 1048576 + 262144 + 65536 + 16384;      // 1392640
  const size_t tex_bytes = n_texel * CH * sizeof(__half);        // ~44.6 MB
  const size_t ws2_bytes = (size_t)NPIX * CH * sizeof(__half);   // 32 MB
  const size_t rec_bytes = (size_t)NPIX * sizeof(float4);        // 16 MB
  const size_t need_bin  = ws2_bytes + tex_bytes + rec_bytes;
  const size_t need_f16  = tex_bytes;

  if (ws_size >= need_bin) {
    char* base = (char*)d_ws;
    __half* ws2    = (__half*)base;
    __half* w1     = (__half*)(base + ws2_bytes);
    __half* w2     = w1 + (size_t)1048576 * CH;
    __half* w3     = w2 + (size_t)262144 * CH;
    __half* w4     = w3 + (size_t)65536 * CH;
    float4* pixrec = (float4*)(base + ws2_bytes + tex_bytes);
    // Sort metadata aliases into ws2 (dead once gather starts writing ws2):
    unsigned* hist    = (unsigned*)base;                          // 4 MB
    unsigned* partial = hist + (size_t)NBLK_SORT * NBINS;         // 256 KB
    unsigned* totals  = partial + (size_t)SEGS * NBINS;           // 16 KB
    unsigned* binbase = totals + NBINS;                           // 16 KB

    interleave_all_kernel<<<(int)(n_texel / 256), 256, 0, stream>>>(
        l1, l2, l3, l4, w1, w2, w3, w4);
    hist_kernel<<<NBLK_SORT, 256, 0, stream>>>((const float2*)x, hist);
    segsum_kernel<<<SEGS * NBINS / 256, 256, 0, stream>>>(hist, partial);
    segscan_kernel<<<NBINS / 256, 256, 0, stream>>>(partial, totals);
    scan_kernel<<<1, 1024, 0, stream>>>(totals, binbase);
    colscan_kernel<<<SEGS * NBINS / 256, 256, 0, stream>>>(hist, partial, binbase);
    scatter2_kernel<<<NBLK_SORT, 256, 0, stream>>>((const float2*)x, msk, hist, pixrec);
    gather_binned2_kernel<<<NPIX * 2 / 256, 256, 0, stream>>>(pixrec, w1, w2, w3, w4, ws2);
    unscatter16_kernel<<<NPIX / 4 / 256, 256, 0, stream>>>(ws2, out);
  } else if (ws_size >= need_f16) {
    __half* w1 = (__half*)d_ws;
    __half* w2 = w1 + (size_t)1048576 * CH;
    __half* w3 = w2 + (size_t)262144 * CH;
    __half* w4 = w3 + (size_t)65536 * CH;
    interleave_all_kernel<<<(int)(n_texel / 256), 256, 0, stream>>>(
        l1, l2, l3, l4, w1, w2, w3, w4);
    gather_hwc16_kernel<<<NPIX / 256, 256, 0, stream>>>(x, msk, w1, w2, w3, w4, out);
  } else {
    gather_chw_kernel<<<NPIX / 256, 256, 0, stream>>>(x, msk, l1, l2, l3, l4, out);
  }
}